// Round 6
// baseline (1379.484 us; speedup 1.0000x reference)
//
#include <hip/hip_runtime.h>

typedef __attribute__((ext_vector_type(8))) short short8;
typedef __attribute__((ext_vector_type(4))) float f32x4;

#define NN 100000
#define NE 600000
#define RR 128
#define HH 256
#define NB_SCAN 98     // ceil(NN/1024)
#define SEGB 16384     // per-seg LDS bytes (64 rows x 256B)

__device__ __forceinline__ unsigned short f2bf(float f) {
    unsigned u = __builtin_bit_cast(unsigned, f);
    u = (u + 0x7fffu + ((u >> 16) & 1u)) >> 16;   // RNE
    return (unsigned short)u;
}

// pack two f32 -> one dword of 2 bf16 (round-half-up), 3 VALU ops
__device__ __forceinline__ unsigned pkbf(float lo, float hi) {
    unsigned a = __builtin_bit_cast(unsigned, lo) + 0x8000u;
    unsigned b = __builtin_bit_cast(unsigned, hi) + 0x8000u;
    return __builtin_amdgcn_perm(b, a, 0x07060302);  // {b.hi16, a.hi16}
}
__device__ __forceinline__ float bflo(unsigned u) {
    return __builtin_bit_cast(float, u << 16);
}
__device__ __forceinline__ float bfhi(unsigned u) {
    return __builtin_bit_cast(float, u & 0xffff0000u);
}

// LDS XOR swizzle: spread 16B blocks of a row across bank groups
__device__ __forceinline__ int swz(int byteoff, int row) {
    return byteoff ^ ((row & 7) << 4);
}

__global__ __launch_bounds__(256) void transpose_cast(const float* __restrict__ src,
                                                      unsigned short* __restrict__ dst,
                                                      int K, int C) {
    int i = blockIdx.x * 256 + threadIdx.x;
    if (i >= K * C) return;
    int c = i / K, k = i - c * K;
    dst[i] = f2bf(src[k * C + c]);   // dst[c][k] = src[k][c]
}

// ---------------- CSR build ----------------
__global__ __launch_bounds__(256) void count_kernel(const int* __restrict__ esrc,
                                                    const int* __restrict__ edst,
                                                    int* __restrict__ cnt) {
    int i = blockIdx.x * 256 + threadIdx.x;
    if (i < NE) {
        atomicAdd(&cnt[esrc[i]], 1);
        atomicAdd(&cnt[edst[i]], 1);
    }
}

__global__ __launch_bounds__(1024) void scan_part(const int* __restrict__ cnt,
                                                  int* __restrict__ excl,
                                                  int* __restrict__ bsum) {
    __shared__ int wsum[16];
    const int tid = threadIdx.x;
    const int lane = tid & 63, w = tid >> 6;
    int i = blockIdx.x * 1024 + tid;
    int v = (i < NN) ? cnt[i] : 0;
    int s = v;
    #pragma unroll
    for (int d = 1; d < 64; d <<= 1) {
        int t = __shfl_up(s, d, 64);
        if (lane >= d) s += t;
    }
    if (lane == 63) wsum[w] = s;
    __syncthreads();
    if (w == 0) {
        int x = (lane < 16) ? wsum[lane] : 0;
        int sx = x;
        #pragma unroll
        for (int d = 1; d < 16; d <<= 1) {
            int t = __shfl_up(sx, d, 64);
            if (lane >= d) sx += t;
        }
        if (lane < 16) wsum[lane] = sx - x;          // exclusive wave offset
        if (lane == 15) bsum[blockIdx.x] = sx;       // block total
    }
    __syncthreads();
    if (i < NN) excl[i] = wsum[w] + (s - v);
}

__global__ void scan_tops(int* __restrict__ bsum, int* __restrict__ offs_nn) {
    if (threadIdx.x == 0) {
        int run = 0;
        for (int b = 0; b < NB_SCAN; ++b) { int t = bsum[b]; bsum[b] = run; run += t; }
        *offs_nn = run;   // offs[NN] = 2*NE
    }
}

__global__ __launch_bounds__(1024) void scan_add(int* __restrict__ offs,
                                                 const int* __restrict__ bsum,
                                                 int* __restrict__ cur) {
    int i = blockIdx.x * 1024 + threadIdx.x;
    if (i < NN) { int v = offs[i] + bsum[blockIdx.x]; offs[i] = v; cur[i] = v; }
}

__global__ __launch_bounds__(256) void fill_kernel(const int* __restrict__ esrc,
                                                   const int* __restrict__ edst,
                                                   int* __restrict__ cur,
                                                   int* __restrict__ adj,
                                                   int* __restrict__ pos_s,
                                                   int* __restrict__ pos_d) {
    int i = blockIdx.x * 256 + threadIdx.x;
    if (i < NE) {
        int p = atomicAdd(&cur[esrc[i]], 1);
        adj[p] = i; pos_s[i] = p;
        int q = atomicAdd(&cur[edst[i]], 1);
        adj[q] = i; pos_d[i] = q;
    }
}

// ---------------- edge kernel: seg-dbuf staging + MLP + optional CSR scatter ----------------
template<bool SCATTER>
__global__ __launch_bounds__(512, 8) void edge_kernel(
    const float* __restrict__ node_rep, const float* __restrict__ edge_attr,
    const int* __restrict__ esrc, const int* __restrict__ edst,
    const unsigned short* __restrict__ w1t, const float* __restrict__ b1,
    const unsigned short* __restrict__ w2t, const float* __restrict__ b2,
    const int* __restrict__ pos_s, const int* __restrict__ pos_d,
    unsigned short* __restrict__ e2ncsr,
    float* __restrict__ edge_out)
{
    __shared__ char Sbuf[2 * SEGB];   // two 16KB seg buffers; H aliases all 32KB
    const int tid = threadIdx.x;
    const int e0 = blockIdx.x * 64;
    const int lane = tid & 63, wave = tid >> 6;
    const int l15 = lane & 15, l4 = lane >> 4;
    const int hbase = wave * 32;

    // lane r holds index/pos data of edge e0+r (same across all waves)
    const int sv = esrc[e0 + lane];
    const int dv = edst[e0 + lane];
    int psv = 0, pdv = 0;
    if (SCATTER) { psv = pos_s[e0 + lane]; pdv = pos_d[e0 + lane]; }

    // staging geometry: 512 threads cover 64 rows x 32 float4 per seg
    const int c4 = tid & 31;
    const int row_b = tid >> 5;           // add j*16, j=0..3

    float4 ga[4];

    // ---- stage segA (edge_attr) -> S0 ----
    #pragma unroll
    for (int j = 0; j < 4; ++j) {
        int row = row_b + j * 16;
        ga[j] = *reinterpret_cast<const float4*>(edge_attr + (size_t)(e0 + row) * RR + c4 * 4);
    }
    #pragma unroll
    for (int j = 0; j < 4; ++j) {
        int row = row_b + j * 16;
        uint2 u; u.x = pkbf(ga[j].x, ga[j].y); u.y = pkbf(ga[j].z, ga[j].w);
        *reinterpret_cast<uint2*>(&Sbuf[swz(row * 256 + c4 * 8, row)]) = u;
    }
    __syncthreads();   // S0 = segA ready

    f32x4 acc[2][4] = {};

#define GEMM1_SEG(SEGIDX, SBASE)                                                     \
    _Pragma("unroll")                                                                \
    for (int kk2 = 0; kk2 < 4; ++kk2) {                                              \
        const int koel = kk2 * 32 + l4 * 8;                                          \
        short8 bfr[4];                                                               \
        _Pragma("unroll")                                                            \
        for (int et = 0; et < 4; ++et) {                                             \
            int rw = et * 16 + l15;                                                  \
            bfr[et] = *reinterpret_cast<const short8*>(                              \
                &Sbuf[(SBASE) + swz(rw * 256 + koel * 2, rw)]);                      \
        }                                                                            \
        _Pragma("unroll")                                                            \
        for (int ht = 0; ht < 2; ++ht) {                                             \
            short8 afr = *reinterpret_cast<const short8*>(                           \
                w1t + (size_t)(hbase + ht * 16 + l15) * 384 + (SEGIDX) * 128 + koel);\
            _Pragma("unroll")                                                        \
            for (int et = 0; et < 4; ++et)                                           \
                acc[ht][et] = __builtin_amdgcn_mfma_f32_16x16x32_bf16(               \
                    afr, bfr[et], acc[ht][et], 0, 0, 0);                             \
        }                                                                            \
    }

    // ---- issue segB loads (src nodes); compute segA; write segB -> S1 ----
    #pragma unroll
    for (int j = 0; j < 4; ++j) {
        int row = row_b + j * 16;
        int ns = __shfl(sv, row);
        ga[j] = *reinterpret_cast<const float4*>(node_rep + (size_t)ns * RR + c4 * 4);
    }
    GEMM1_SEG(0, 0)
    #pragma unroll
    for (int j = 0; j < 4; ++j) {
        int row = row_b + j * 16;
        uint2 u; u.x = pkbf(ga[j].x, ga[j].y); u.y = pkbf(ga[j].z, ga[j].w);
        *reinterpret_cast<uint2*>(&Sbuf[SEGB + swz(row * 256 + c4 * 8, row)]) = u;
    }
    __syncthreads();   // S1 = segB ready (S0 fully consumed)

    // ---- issue segC loads (dst nodes); compute segB; write segC -> S0 ----
    #pragma unroll
    for (int j = 0; j < 4; ++j) {
        int row = row_b + j * 16;
        int nd = __shfl(dv, row);
        ga[j] = *reinterpret_cast<const float4*>(node_rep + (size_t)nd * RR + c4 * 4);
    }
    GEMM1_SEG(1, SEGB)
    #pragma unroll
    for (int j = 0; j < 4; ++j) {
        int row = row_b + j * 16;
        uint2 u; u.x = pkbf(ga[j].x, ga[j].y); u.y = pkbf(ga[j].z, ga[j].w);
        *reinterpret_cast<uint2*>(&Sbuf[swz(row * 256 + c4 * 8, row)]) = u;
    }
    __syncthreads();   // S0 = segC ready (S1 consumed)

    GEMM1_SEG(2, 0)
    __syncthreads();   // all A reads done; alias H over full 32KB
#undef GEMM1_SEG

    // ---- H = relu(acc + b1) -> bf16 LDS (row stride 512B, swizzled) ----
    #pragma unroll
    for (int ht = 0; ht < 2; ++ht) {
        const int h0 = hbase + ht * 16 + l4 * 4;
        float4 bb = *reinterpret_cast<const float4*>(b1 + h0);
        #pragma unroll
        for (int et = 0; et < 4; ++et) {
            int e = et * 16 + l15;
            float x0 = fmaxf(acc[ht][et][0] + bb.x, 0.f);
            float x1 = fmaxf(acc[ht][et][1] + bb.y, 0.f);
            float x2 = fmaxf(acc[ht][et][2] + bb.z, 0.f);
            float x3 = fmaxf(acc[ht][et][3] + bb.w, 0.f);
            uint2 u; u.x = pkbf(x0, x1); u.y = pkbf(x2, x3);
            *reinterpret_cast<uint2*>(&Sbuf[swz(e * 512 + h0 * 2, e)]) = u;
        }
    }
    __syncthreads();   // H ready

    // ---- GEMM2': D2'[c][e] = sum_h W2T[c][h] * H[e][h] ----
    f32x4 acc2[4] = {};
    const int cbase = wave * 16;
    #pragma unroll
    for (int kk = 0; kk < 256; kk += 32) {
        const int koel = kk + l4 * 8;
        short8 afr = *reinterpret_cast<const short8*>(
            w2t + (size_t)(cbase + l15) * 256 + koel);
        #pragma unroll
        for (int et = 0; et < 4; ++et) {
            int rw = et * 16 + l15;
            short8 bfr = *reinterpret_cast<const short8*>(&Sbuf[swz(rw * 512 + koel * 2, rw)]);
            acc2[et] = __builtin_amdgcn_mfma_f32_16x16x32_bf16(afr, bfr, acc2[et], 0, 0, 0);
        }
    }

    // ---- epilogue: bias + store edge_out (+ bf16 CSR scatter) ----
    {
        const int c0 = cbase + l4 * 4;
        float4 bb = *reinterpret_cast<const float4*>(b2 + c0);
        #pragma unroll
        for (int et = 0; et < 4; ++et) {
            int e = et * 16 + l15;
            float4 v;
            v.x = acc2[et][0] + bb.x;
            v.y = acc2[et][1] + bb.y;
            v.z = acc2[et][2] + bb.z;
            v.w = acc2[et][3] + bb.w;
            *reinterpret_cast<float4*>(edge_out + (size_t)(e0 + e) * RR + c0) = v;
            if (SCATTER) {
                uint2 u; u.x = pkbf(v.x, v.y); u.y = pkbf(v.z, v.w);
                int p = __shfl(psv, e);
                *reinterpret_cast<uint2*>(e2ncsr + (size_t)p * RR + c0) = u;
                int q = __shfl(pdv, e);
                *reinterpret_cast<uint2*>(e2ncsr + (size_t)q * RR + c0) = u;
            }
        }
    }
}

// ---------------- node kernel (primary): streamed bf16 CSR gather + MLP ----------------
__global__ __launch_bounds__(512, 8) void node_kernel_csr(
    const float* __restrict__ node_rep,
    const int* __restrict__ offs, const unsigned short* __restrict__ e2ncsr,
    const unsigned short* __restrict__ w1t, const float* __restrict__ b1,
    const unsigned short* __restrict__ w2t, const float* __restrict__ b2,
    float* __restrict__ out)
{
    __shared__ char Abuf[64 * 512];   // A-tile (256 bf16/row); H aliases after GEMM1
    const int tid = threadIdx.x;
    const int n0 = blockIdx.x * 64;
    const int r = tid >> 3, t8 = tid & 7;     // 8 threads/row, 16 elements each
    const int n = n0 + r;
    const int nc = (n < NN) ? n : NN - 1;

    // node_rep -> A cols [t8*16, +16)
    {
        const f32x4* src = reinterpret_cast<const f32x4*>(node_rep + (size_t)nc * RR + t8 * 16);
        f32x4 v0 = src[0], v1 = src[1], v2 = src[2], v3 = src[3];
        uint2 u;
        int b = r * 512 + t8 * 32;
        u.x = pkbf(v0[0], v0[1]); u.y = pkbf(v0[2], v0[3]);
        *reinterpret_cast<uint2*>(&Abuf[swz(b, r)]) = u;
        u.x = pkbf(v1[0], v1[1]); u.y = pkbf(v1[2], v1[3]);
        *reinterpret_cast<uint2*>(&Abuf[swz(b + 8, r)]) = u;
        u.x = pkbf(v2[0], v2[1]); u.y = pkbf(v2[2], v2[3]);
        *reinterpret_cast<uint2*>(&Abuf[swz(b + 16, r)]) = u;
        u.x = pkbf(v3[0], v3[1]); u.y = pkbf(v3[2], v3[3]);
        *reinterpret_cast<uint2*>(&Abuf[swz(b + 24, r)]) = u;
    }
    // e2n: sequential bf16 CSR rows, f32 accumulate -> A cols [128+t8*16, +16)
    {
        f32x4 a0 = {}, a1 = {}, a2 = {}, a3 = {};
        if (n < NN) {
            int p = offs[n];
            const int pe = offs[n + 1];
            for (; p + 1 < pe; p += 2) {
                const uint4* ra = reinterpret_cast<const uint4*>(e2ncsr + (size_t)p * RR + t8 * 16);
                const uint4* rb = reinterpret_cast<const uint4*>(e2ncsr + (size_t)(p + 1) * RR + t8 * 16);
                uint4 xa = ra[0], ya = ra[1];
                uint4 xb = rb[0], yb = rb[1];
                a0[0] += bflo(xa.x); a0[1] += bfhi(xa.x); a0[2] += bflo(xa.y); a0[3] += bfhi(xa.y);
                a1[0] += bflo(xa.z); a1[1] += bfhi(xa.z); a1[2] += bflo(xa.w); a1[3] += bfhi(xa.w);
                a2[0] += bflo(ya.x); a2[1] += bfhi(ya.x); a2[2] += bflo(ya.y); a2[3] += bfhi(ya.y);
                a3[0] += bflo(ya.z); a3[1] += bfhi(ya.z); a3[2] += bflo(ya.w); a3[3] += bfhi(ya.w);
                a0[0] += bflo(xb.x); a0[1] += bfhi(xb.x); a0[2] += bflo(xb.y); a0[3] += bfhi(xb.y);
                a1[0] += bflo(xb.z); a1[1] += bfhi(xb.z); a1[2] += bflo(xb.w); a1[3] += bfhi(xb.w);
                a2[0] += bflo(yb.x); a2[1] += bfhi(yb.x); a2[2] += bflo(yb.y); a2[3] += bfhi(yb.y);
                a3[0] += bflo(yb.z); a3[1] += bfhi(yb.z); a3[2] += bflo(yb.w); a3[3] += bfhi(yb.w);
            }
            if (p < pe) {
                const uint4* ra = reinterpret_cast<const uint4*>(e2ncsr + (size_t)p * RR + t8 * 16);
                uint4 xa = ra[0], ya = ra[1];
                a0[0] += bflo(xa.x); a0[1] += bfhi(xa.x); a0[2] += bflo(xa.y); a0[3] += bfhi(xa.y);
                a1[0] += bflo(xa.z); a1[1] += bfhi(xa.z); a1[2] += bflo(xa.w); a1[3] += bfhi(xa.w);
                a2[0] += bflo(ya.x); a2[1] += bfhi(ya.x); a2[2] += bflo(ya.y); a2[3] += bfhi(ya.y);
                a3[0] += bflo(ya.z); a3[1] += bfhi(ya.z); a3[2] += bflo(ya.w); a3[3] += bfhi(ya.w);
            }
        }
        uint2 u;
        int b = r * 512 + 256 + t8 * 32;
        u.x = pkbf(a0[0], a0[1]); u.y = pkbf(a0[2], a0[3]);
        *reinterpret_cast<uint2*>(&Abuf[swz(b, r)]) = u;
        u.x = pkbf(a1[0], a1[1]); u.y = pkbf(a1[2], a1[3]);
        *reinterpret_cast<uint2*>(&Abuf[swz(b + 8, r)]) = u;
        u.x = pkbf(a2[0], a2[1]); u.y = pkbf(a2[2], a2[3]);
        *reinterpret_cast<uint2*>(&Abuf[swz(b + 16, r)]) = u;
        u.x = pkbf(a3[0], a3[1]); u.y = pkbf(a3[2], a3[3]);
        *reinterpret_cast<uint2*>(&Abuf[swz(b + 24, r)]) = u;
    }
    __syncthreads();

    const int lane = tid & 63, wave = tid >> 6;
    const int l15 = lane & 15, l4 = lane >> 4;
    const int hbase = wave * 32;

    // GEMM1: k = 256
    f32x4 acc[2][4] = {};
    #pragma unroll
    for (int kk = 0; kk < 8; ++kk) {
        const int koel = kk * 32 + l4 * 8;
        short8 bfr[4];
        #pragma unroll
        for (int et = 0; et < 4; ++et) {
            int rw = et * 16 + l15;
            bfr[et] = *reinterpret_cast<const short8*>(&Abuf[swz(rw * 512 + koel * 2, rw)]);
        }
        #pragma unroll
        for (int ht = 0; ht < 2; ++ht) {
            short8 afr = *reinterpret_cast<const short8*>(
                w1t + (size_t)(hbase + ht * 16 + l15) * 256 + koel);
            #pragma unroll
            for (int et = 0; et < 4; ++et)
                acc[ht][et] = __builtin_amdgcn_mfma_f32_16x16x32_bf16(afr, bfr[et], acc[ht][et], 0, 0, 0);
        }
    }
    __syncthreads();   // A reads done; alias H

    #pragma unroll
    for (int ht = 0; ht < 2; ++ht) {
        const int h0 = hbase + ht * 16 + l4 * 4;
        float4 bb = *reinterpret_cast<const float4*>(b1 + h0);
        #pragma unroll
        for (int et = 0; et < 4; ++et) {
            int e = et * 16 + l15;
            float x0 = fmaxf(acc[ht][et][0] + bb.x, 0.f);
            float x1 = fmaxf(acc[ht][et][1] + bb.y, 0.f);
            float x2 = fmaxf(acc[ht][et][2] + bb.z, 0.f);
            float x3 = fmaxf(acc[ht][et][3] + bb.w, 0.f);
            uint2 u; u.x = pkbf(x0, x1); u.y = pkbf(x2, x3);
            *reinterpret_cast<uint2*>(&Abuf[swz(e * 512 + h0 * 2, e)]) = u;
        }
    }
    __syncthreads();

    // GEMM2
    f32x4 acc2[4] = {};
    const int cbase = wave * 16;
    #pragma unroll
    for (int kk = 0; kk < 256; kk += 32) {
        const int koel = kk + l4 * 8;
        short8 afr = *reinterpret_cast<const short8*>(
            w2t + (size_t)(cbase + l15) * 256 + koel);
        #pragma unroll
        for (int et = 0; et < 4; ++et) {
            int rw = et * 16 + l15;
            short8 bfr = *reinterpret_cast<const short8*>(&Abuf[swz(rw * 512 + koel * 2, rw)]);
            acc2[et] = __builtin_amdgcn_mfma_f32_16x16x32_bf16(afr, bfr, acc2[et], 0, 0, 0);
        }
    }

    {
        const int c0 = cbase + l4 * 4;
        float4 bb = *reinterpret_cast<const float4*>(b2 + c0);
        #pragma unroll
        for (int et = 0; et < 4; ++et) {
            int nn2 = n0 + et * 16 + l15;
            if (nn2 < NN) {
                float4 v;
                v.x = acc2[et][0] + bb.x;
                v.y = acc2[et][1] + bb.y;
                v.z = acc2[et][2] + bb.z;
                v.w = acc2[et][3] + bb.w;
                *reinterpret_cast<float4*>(out + (size_t)nn2 * RR + c0) = v;
            }
        }
    }
}

// ---------------- node kernel (fallback): adj-gather from f32 edge_out ----------------
__global__ __launch_bounds__(512, 5) void node_kernel_adj(
    const float* __restrict__ node_rep,
    const int* __restrict__ offs, const int* __restrict__ adj,
    const float* __restrict__ edge_out,
    const unsigned short* __restrict__ w1t, const float* __restrict__ b1,
    const unsigned short* __restrict__ w2t, const float* __restrict__ b2,
    float* __restrict__ out)
{
    __shared__ char Abuf[64 * 512];
    const int tid = threadIdx.x;
    const int n0 = blockIdx.x * 64;
    const int r = tid >> 3, t8 = tid & 7;
    const int n = n0 + r;
    const int nc = (n < NN) ? n : NN - 1;

    {
        const f32x4* src = reinterpret_cast<const f32x4*>(node_rep + (size_t)nc * RR + t8 * 16);
        f32x4 v0 = src[0], v1 = src[1], v2 = src[2], v3 = src[3];
        uint2 u;
        int b = r * 512 + t8 * 32;
        u.x = pkbf(v0[0], v0[1]); u.y = pkbf(v0[2], v0[3]);
        *reinterpret_cast<uint2*>(&Abuf[swz(b, r)]) = u;
        u.x = pkbf(v1[0], v1[1]); u.y = pkbf(v1[2], v1[3]);
        *reinterpret_cast<uint2*>(&Abuf[swz(b + 8, r)]) = u;
        u.x = pkbf(v2[0], v2[1]); u.y = pkbf(v2[2], v2[3]);
        *reinterpret_cast<uint2*>(&Abuf[swz(b + 16, r)]) = u;
        u.x = pkbf(v3[0], v3[1]); u.y = pkbf(v3[2], v3[3]);
        *reinterpret_cast<uint2*>(&Abuf[swz(b + 24, r)]) = u;
    }
    {
        f32x4 a0 = {}, a1 = {}, a2 = {}, a3 = {};
        if (n < NN) {
            int p = offs[n];
            const int pe = offs[n + 1];
            for (; p + 3 < pe; p += 4) {
                int ea = adj[p], eb = adj[p + 1], ec = adj[p + 2], ed = adj[p + 3];
                const f32x4* ra = reinterpret_cast<const f32x4*>(edge_out + (size_t)ea * RR + t8 * 16);
                const f32x4* rb = reinterpret_cast<const f32x4*>(edge_out + (size_t)eb * RR + t8 * 16);
                const f32x4* rc = reinterpret_cast<const f32x4*>(edge_out + (size_t)ec * RR + t8 * 16);
                const f32x4* rd = reinterpret_cast<const f32x4*>(edge_out + (size_t)ed * RR + t8 * 16);
                a0 += ra[0]; a1 += ra[1]; a2 += ra[2]; a3 += ra[3];
                a0 += rb[0]; a1 += rb[1]; a2 += rb[2]; a3 += rb[3];
                a0 += rc[0]; a1 += rc[1]; a2 += rc[2]; a3 += rc[3];
                a0 += rd[0]; a1 += rd[1]; a2 += rd[2]; a3 += rd[3];
            }
            for (; p < pe; ++p) {
                int e = adj[p];
                const f32x4* rr = reinterpret_cast<const f32x4*>(edge_out + (size_t)e * RR + t8 * 16);
                a0 += rr[0]; a1 += rr[1]; a2 += rr[2]; a3 += rr[3];
            }
        }
        uint2 u;
        int b = r * 512 + 256 + t8 * 32;
        u.x = pkbf(a0[0], a0[1]); u.y = pkbf(a0[2], a0[3]);
        *reinterpret_cast<uint2*>(&Abuf[swz(b, r)]) = u;
        u.x = pkbf(a1[0], a1[1]); u.y = pkbf(a1[2], a1[3]);
        *reinterpret_cast<uint2*>(&Abuf[swz(b + 8, r)]) = u;
        u.x = pkbf(a2[0], a2[1]); u.y = pkbf(a2[2], a2[3]);
        *reinterpret_cast<uint2*>(&Abuf[swz(b + 16, r)]) = u;
        u.x = pkbf(a3[0], a3[1]); u.y = pkbf(a3[2], a3[3]);
        *reinterpret_cast<uint2*>(&Abuf[swz(b + 24, r)]) = u;
    }
    __syncthreads();

    const int lane = tid & 63, wave = tid >> 6;
    const int l15 = lane & 15, l4 = lane >> 4;
    const int hbase = wave * 32;

    f32x4 acc[2][4] = {};
    #pragma unroll
    for (int kk = 0; kk < 8; ++kk) {
        const int koel = kk * 32 + l4 * 8;
        short8 bfr[4];
        #pragma unroll
        for (int et = 0; et < 4; ++et) {
            int rw = et * 16 + l15;
            bfr[et] = *reinterpret_cast<const short8*>(&Abuf[swz(rw * 512 + koel * 2, rw)]);
        }
        #pragma unroll
        for (int ht = 0; ht < 2; ++ht) {
            short8 afr = *reinterpret_cast<const short8*>(
                w1t + (size_t)(hbase + ht * 16 + l15) * 256 + koel);
            #pragma unroll
            for (int et = 0; et < 4; ++et)
                acc[ht][et] = __builtin_amdgcn_mfma_f32_16x16x32_bf16(afr, bfr[et], acc[ht][et], 0, 0, 0);
        }
    }
    __syncthreads();

    #pragma unroll
    for (int ht = 0; ht < 2; ++ht) {
        const int h0 = hbase + ht * 16 + l4 * 4;
        float4 bb = *reinterpret_cast<const float4*>(b1 + h0);
        #pragma unroll
        for (int et = 0; et < 4; ++et) {
            int e = et * 16 + l15;
            float x0 = fmaxf(acc[ht][et][0] + bb.x, 0.f);
            float x1 = fmaxf(acc[ht][et][1] + bb.y, 0.f);
            float x2 = fmaxf(acc[ht][et][2] + bb.z, 0.f);
            float x3 = fmaxf(acc[ht][et][3] + bb.w, 0.f);
            uint2 u; u.x = pkbf(x0, x1); u.y = pkbf(x2, x3);
            *reinterpret_cast<uint2*>(&Abuf[swz(e * 512 + h0 * 2, e)]) = u;
        }
    }
    __syncthreads();

    f32x4 acc2[4] = {};
    const int cbase = wave * 16;
    #pragma unroll
    for (int kk = 0; kk < 256; kk += 32) {
        const int koel = kk + l4 * 8;
        short8 afr = *reinterpret_cast<const short8*>(
            w2t + (size_t)(cbase + l15) * 256 + koel);
        #pragma unroll
        for (int et = 0; et < 4; ++et) {
            int rw = et * 16 + l15;
            short8 bfr = *reinterpret_cast<const short8*>(&Abuf[swz(rw * 512 + koel * 2, rw)]);
            acc2[et] = __builtin_amdgcn_mfma_f32_16x16x32_bf16(afr, bfr, acc2[et], 0, 0, 0);
        }
    }

    {
        const int c0 = cbase + l4 * 4;
        float4 bb = *reinterpret_cast<const float4*>(b2 + c0);
        #pragma unroll
        for (int et = 0; et < 4; ++et) {
            int nn2 = n0 + et * 16 + l15;
            if (nn2 < NN) {
                float4 v;
                v.x = acc2[et][0] + bb.x;
                v.y = acc2[et][1] + bb.y;
                v.z = acc2[et][2] + bb.z;
                v.w = acc2[et][3] + bb.w;
                *reinterpret_cast<float4*>(out + (size_t)nn2 * RR + c0) = v;
            }
        }
    }
}

extern "C" void kernel_launch(void* const* d_in, const int* in_sizes, int n_in,
                              void* d_out, int out_size, void* d_ws, size_t ws_size,
                              hipStream_t stream) {
    const float* node_rep  = (const float*)d_in[0];
    const float* edge_attr = (const float*)d_in[1];
    const int*   esrc      = (const int*)d_in[2];
    const int*   edst      = (const int*)d_in[3];
    const float* W1e = (const float*)d_in[4];
    const float* b1e = (const float*)d_in[5];
    const float* W2e = (const float*)d_in[6];
    const float* b2e = (const float*)d_in[7];
    const float* W1n = (const float*)d_in[8];
    const float* b1n = (const float*)d_in[9];
    const float* W2n = (const float*)d_in[10];
    const float* b2n = (const float*)d_in[11];

    float* out      = (float*)d_out;
    float* node_out = out;                          // N*R
    float* edge_out = out + (size_t)NN * RR;        // E*R

    // workspace layout (bytes)
    char* ws = (char*)d_ws;
    unsigned short* w1et = (unsigned short*)ws;                 // [256][384]
    unsigned short* w2et = w1et + 256 * 384;                    // [128][256]
    unsigned short* w1nt = w2et + 128 * 256;                    // [256][256]
    unsigned short* w2nt = w1nt + 256 * 256;                    // [128][256]
    size_t off = 458752;
    int* cnt  = (int*)(ws + off);               off += 400000;  // [NN] (fill cursor)
    int* offs = (int*)(ws + off);               off += 400008;  // [NN+1]
    int* pos_s = (int*)(ws + off);              off += 2400000; // [NE]
    int* pos_d = (int*)(ws + off);              off += 2400000; // [NE]
    int* adj  = (int*)(ws + off);               off += 4800000; // [2*NE]
    int* bsum = (int*)(ws + off);               off += 512;     // [NB_SCAN]
    unsigned short* e2ncsr = (unsigned short*)(ws + off);       // [2*NE][128] bf16
    const size_t need = off + (size_t)2 * NE * RR * sizeof(unsigned short);
    const bool big = ws_size >= need;

    hipMemsetAsync(cnt, 0, (size_t)NN * sizeof(int), stream);

    transpose_cast<<<(384 * 256 + 255) / 256, 256, 0, stream>>>(W1e, w1et, 384, 256);
    transpose_cast<<<(256 * 128 + 255) / 256, 256, 0, stream>>>(W2e, w2et, 256, 128);
    transpose_cast<<<(256 * 256 + 255) / 256, 256, 0, stream>>>(W1n, w1nt, 256, 256);
    transpose_cast<<<(256 * 128 + 255) / 256, 256, 0, stream>>>(W2n, w2nt, 256, 128);

    count_kernel<<<(NE + 255) / 256, 256, 0, stream>>>(esrc, edst, cnt);
    scan_part<<<NB_SCAN, 1024, 0, stream>>>(cnt, offs, bsum);
    scan_tops<<<1, 64, 0, stream>>>(bsum, offs + NN);
    scan_add<<<NB_SCAN, 1024, 0, stream>>>(offs, bsum, cnt);
    fill_kernel<<<(NE + 255) / 256, 256, 0, stream>>>(esrc, edst, cnt, adj, pos_s, pos_d);

    if (big) {
        edge_kernel<true><<<NE / 64, 512, 0, stream>>>(node_rep, edge_attr, esrc, edst,
                                                       w1et, b1e, w2et, b2e,
                                                       pos_s, pos_d, e2ncsr, edge_out);
        node_kernel_csr<<<(NN + 63) / 64, 512, 0, stream>>>(node_rep, offs, e2ncsr,
                                                            w1nt, b1n, w2nt, b2n, node_out);
    } else {
        edge_kernel<false><<<NE / 64, 512, 0, stream>>>(node_rep, edge_attr, esrc, edst,
                                                        w1et, b1e, w2et, b2e,
                                                        pos_s, pos_d, e2ncsr, edge_out);
        node_kernel_adj<<<(NN + 63) / 64, 512, 0, stream>>>(node_rep, offs, adj, edge_out,
                                                            w1nt, b1n, w2nt, b2n, node_out);
    }
}

// Round 7
// 1202.638 us; speedup vs baseline: 1.1470x; 1.1470x over previous
//
#include <hip/hip_runtime.h>

typedef __attribute__((ext_vector_type(8))) short short8;
typedef __attribute__((ext_vector_type(4))) float f32x4;

#define NN 100000
#define NE 600000
#define RR 128
#define HH 256
#define NB_SCAN 98     // ceil(NN/1024)
#define SEGB 16384     // per-seg LDS bytes (64 rows x 256B)

__device__ __forceinline__ unsigned short f2bf(float f) {
    unsigned u = __builtin_bit_cast(unsigned, f);
    u = (u + 0x7fffu + ((u >> 16) & 1u)) >> 16;   // RNE
    return (unsigned short)u;
}

// pack two f32 -> one dword of 2 bf16 (round-half-up), 3 VALU ops
__device__ __forceinline__ unsigned pkbf(float lo, float hi) {
    unsigned a = __builtin_bit_cast(unsigned, lo) + 0x8000u;
    unsigned b = __builtin_bit_cast(unsigned, hi) + 0x8000u;
    return __builtin_amdgcn_perm(b, a, 0x07060302);  // {b.hi16, a.hi16}
}

// LDS XOR swizzle: spread 16B blocks of a row across bank groups
__device__ __forceinline__ int swz(int byteoff, int row) {
    return byteoff ^ ((row & 7) << 4);
}

__global__ __launch_bounds__(256) void transpose_cast(const float* __restrict__ src,
                                                      unsigned short* __restrict__ dst,
                                                      int K, int C) {
    int i = blockIdx.x * 256 + threadIdx.x;
    if (i >= K * C) return;
    int c = i / K, k = i - c * K;
    dst[i] = f2bf(src[k * C + c]);   // dst[c][k] = src[k][c]
}

// ---------------- CSR build ----------------
__global__ __launch_bounds__(256) void count_kernel(const int* __restrict__ esrc,
                                                    const int* __restrict__ edst,
                                                    int* __restrict__ cnt) {
    int i = blockIdx.x * 256 + threadIdx.x;
    if (i < NE) {
        atomicAdd(&cnt[esrc[i]], 1);
        atomicAdd(&cnt[edst[i]], 1);
    }
}

__global__ __launch_bounds__(1024) void scan_part(const int* __restrict__ cnt,
                                                  int* __restrict__ excl,
                                                  int* __restrict__ bsum) {
    __shared__ int wsum[16];
    const int tid = threadIdx.x;
    const int lane = tid & 63, w = tid >> 6;
    int i = blockIdx.x * 1024 + tid;
    int v = (i < NN) ? cnt[i] : 0;
    int s = v;
    #pragma unroll
    for (int d = 1; d < 64; d <<= 1) {
        int t = __shfl_up(s, d, 64);
        if (lane >= d) s += t;
    }
    if (lane == 63) wsum[w] = s;
    __syncthreads();
    if (w == 0) {
        int x = (lane < 16) ? wsum[lane] : 0;
        int sx = x;
        #pragma unroll
        for (int d = 1; d < 16; d <<= 1) {
            int t = __shfl_up(sx, d, 64);
            if (lane >= d) sx += t;
        }
        if (lane < 16) wsum[lane] = sx - x;          // exclusive wave offset
        if (lane == 15) bsum[blockIdx.x] = sx;       // block total
    }
    __syncthreads();
    if (i < NN) excl[i] = wsum[w] + (s - v);
}

__global__ void scan_tops(int* __restrict__ bsum, int* __restrict__ offs_nn) {
    if (threadIdx.x == 0) {
        int run = 0;
        for (int b = 0; b < NB_SCAN; ++b) { int t = bsum[b]; bsum[b] = run; run += t; }
        *offs_nn = run;   // offs[NN] = 2*NE
    }
}

__global__ __launch_bounds__(1024) void scan_add(int* __restrict__ offs,
                                                 const int* __restrict__ bsum,
                                                 int* __restrict__ cur) {
    int i = blockIdx.x * 1024 + threadIdx.x;
    if (i < NN) { int v = offs[i] + bsum[blockIdx.x]; offs[i] = v; cur[i] = v; }
}

__global__ __launch_bounds__(256) void fill_kernel(const int* __restrict__ esrc,
                                                   const int* __restrict__ edst,
                                                   int* __restrict__ cur,
                                                   int* __restrict__ adj) {
    int i = blockIdx.x * 256 + threadIdx.x;
    if (i < NE) {
        int p = atomicAdd(&cur[esrc[i]], 1);
        adj[p] = i;
        int q = atomicAdd(&cur[edst[i]], 1);
        adj[q] = i;
    }
}

// ---------------- edge kernel: seg-dbuf staging + MLP (32KB LDS, 8 waves) ----------------
__global__ __launch_bounds__(512, 8) void edge_kernel(
    const float* __restrict__ node_rep, const float* __restrict__ edge_attr,
    const int* __restrict__ esrc, const int* __restrict__ edst,
    const unsigned short* __restrict__ w1t, const float* __restrict__ b1,
    const unsigned short* __restrict__ w2t, const float* __restrict__ b2,
    float* __restrict__ edge_out)
{
    __shared__ char Sbuf[2 * SEGB];   // two 16KB seg buffers; H aliases all 32KB
    const int tid = threadIdx.x;
    const int e0 = blockIdx.x * 64;
    const int lane = tid & 63, wave = tid >> 6;
    const int l15 = lane & 15, l4 = lane >> 4;
    const int hbase = wave * 32;

    // lane r holds endpoint indices of edge e0+r (same across all waves)
    const int sv = esrc[e0 + lane];
    const int dv = edst[e0 + lane];

    // staging geometry: 512 threads cover 64 rows x 32 float4 per seg
    const int c4 = tid & 31;
    const int row_b = tid >> 5;           // add j*16, j=0..3

    float4 ga[4];

    // ---- stage segA (edge_attr) -> S0 ----
    #pragma unroll
    for (int j = 0; j < 4; ++j) {
        int row = row_b + j * 16;
        ga[j] = *reinterpret_cast<const float4*>(edge_attr + (size_t)(e0 + row) * RR + c4 * 4);
    }
    #pragma unroll
    for (int j = 0; j < 4; ++j) {
        int row = row_b + j * 16;
        uint2 u; u.x = pkbf(ga[j].x, ga[j].y); u.y = pkbf(ga[j].z, ga[j].w);
        *reinterpret_cast<uint2*>(&Sbuf[swz(row * 256 + c4 * 8, row)]) = u;
    }
    __syncthreads();   // S0 = segA ready

    f32x4 acc[2][4] = {};

#define GEMM1_SEG(SEGIDX, SBASE)                                                     \
    _Pragma("unroll")                                                                \
    for (int kk2 = 0; kk2 < 4; ++kk2) {                                              \
        const int koel = kk2 * 32 + l4 * 8;                                          \
        short8 bfr[4];                                                               \
        _Pragma("unroll")                                                            \
        for (int et = 0; et < 4; ++et) {                                             \
            int rw = et * 16 + l15;                                                  \
            bfr[et] = *reinterpret_cast<const short8*>(                              \
                &Sbuf[(SBASE) + swz(rw * 256 + koel * 2, rw)]);                      \
        }                                                                            \
        _Pragma("unroll")                                                            \
        for (int ht = 0; ht < 2; ++ht) {                                             \
            short8 afr = *reinterpret_cast<const short8*>(                           \
                w1t + (size_t)(hbase + ht * 16 + l15) * 384 + (SEGIDX) * 128 + koel);\
            _Pragma("unroll")                                                        \
            for (int et = 0; et < 4; ++et)                                           \
                acc[ht][et] = __builtin_amdgcn_mfma_f32_16x16x32_bf16(               \
                    afr, bfr[et], acc[ht][et], 0, 0, 0);                             \
        }                                                                            \
    }

    // ---- issue segB loads (src nodes); compute segA; write segB -> S1 ----
    #pragma unroll
    for (int j = 0; j < 4; ++j) {
        int row = row_b + j * 16;
        int ns = __shfl(sv, row);
        ga[j] = *reinterpret_cast<const float4*>(node_rep + (size_t)ns * RR + c4 * 4);
    }
    GEMM1_SEG(0, 0)
    #pragma unroll
    for (int j = 0; j < 4; ++j) {
        int row = row_b + j * 16;
        uint2 u; u.x = pkbf(ga[j].x, ga[j].y); u.y = pkbf(ga[j].z, ga[j].w);
        *reinterpret_cast<uint2*>(&Sbuf[SEGB + swz(row * 256 + c4 * 8, row)]) = u;
    }
    __syncthreads();   // S1 = segB ready (S0 fully consumed)

    // ---- issue segC loads (dst nodes); compute segB; write segC -> S0 ----
    #pragma unroll
    for (int j = 0; j < 4; ++j) {
        int row = row_b + j * 16;
        int nd = __shfl(dv, row);
        ga[j] = *reinterpret_cast<const float4*>(node_rep + (size_t)nd * RR + c4 * 4);
    }
    GEMM1_SEG(1, SEGB)
    #pragma unroll
    for (int j = 0; j < 4; ++j) {
        int row = row_b + j * 16;
        uint2 u; u.x = pkbf(ga[j].x, ga[j].y); u.y = pkbf(ga[j].z, ga[j].w);
        *reinterpret_cast<uint2*>(&Sbuf[swz(row * 256 + c4 * 8, row)]) = u;
    }
    __syncthreads();   // S0 = segC ready (S1 consumed)

    GEMM1_SEG(2, 0)
    __syncthreads();   // all A reads done; alias H over full 32KB
#undef GEMM1_SEG

    // ---- H = relu(acc + b1) -> bf16 LDS (row stride 512B, swizzled) ----
    #pragma unroll
    for (int ht = 0; ht < 2; ++ht) {
        const int h0 = hbase + ht * 16 + l4 * 4;
        float4 bb = *reinterpret_cast<const float4*>(b1 + h0);
        #pragma unroll
        for (int et = 0; et < 4; ++et) {
            int e = et * 16 + l15;
            float x0 = fmaxf(acc[ht][et][0] + bb.x, 0.f);
            float x1 = fmaxf(acc[ht][et][1] + bb.y, 0.f);
            float x2 = fmaxf(acc[ht][et][2] + bb.z, 0.f);
            float x3 = fmaxf(acc[ht][et][3] + bb.w, 0.f);
            uint2 u; u.x = pkbf(x0, x1); u.y = pkbf(x2, x3);
            *reinterpret_cast<uint2*>(&Sbuf[swz(e * 512 + h0 * 2, e)]) = u;
        }
    }
    __syncthreads();   // H ready

    // ---- GEMM2': D2'[c][e] = sum_h W2T[c][h] * H[e][h] ----
    f32x4 acc2[4] = {};
    const int cbase = wave * 16;
    #pragma unroll
    for (int kk = 0; kk < 256; kk += 32) {
        const int koel = kk + l4 * 8;
        short8 afr = *reinterpret_cast<const short8*>(
            w2t + (size_t)(cbase + l15) * 256 + koel);
        #pragma unroll
        for (int et = 0; et < 4; ++et) {
            int rw = et * 16 + l15;
            short8 bfr = *reinterpret_cast<const short8*>(&Sbuf[swz(rw * 512 + koel * 2, rw)]);
            acc2[et] = __builtin_amdgcn_mfma_f32_16x16x32_bf16(afr, bfr, acc2[et], 0, 0, 0);
        }
    }

    // ---- epilogue: bias + store edge_out ----
    {
        const int c0 = cbase + l4 * 4;
        float4 bb = *reinterpret_cast<const float4*>(b2 + c0);
        #pragma unroll
        for (int et = 0; et < 4; ++et) {
            int e = et * 16 + l15;
            float4 v;
            v.x = acc2[et][0] + bb.x;
            v.y = acc2[et][1] + bb.y;
            v.z = acc2[et][2] + bb.z;
            v.w = acc2[et][3] + bb.w;
            *reinterpret_cast<float4*>(edge_out + (size_t)(e0 + e) * RR + c0) = v;
        }
    }
}

// ---------------- node kernel: unrolled CSR pull + MLP -> node_out ----------------
__global__ __launch_bounds__(512, 5) void node_kernel(
    const float* __restrict__ node_rep,
    const int* __restrict__ offs, const int* __restrict__ adj,
    const float* __restrict__ edge_out,
    const unsigned short* __restrict__ w1t, const float* __restrict__ b1,
    const unsigned short* __restrict__ w2t, const float* __restrict__ b2,
    float* __restrict__ out)
{
    __shared__ char Abuf[64 * 512];   // A-tile (256 bf16/row); H aliases after GEMM1
    const int tid = threadIdx.x;
    const int n0 = blockIdx.x * 64;
    const int r = tid >> 3, t8 = tid & 7;     // 8 threads/row, 16 elements each
    const int n = n0 + r;
    const int nc = (n < NN) ? n : NN - 1;

    // node_rep -> A cols [t8*16, +16)
    {
        const f32x4* src = reinterpret_cast<const f32x4*>(node_rep + (size_t)nc * RR + t8 * 16);
        f32x4 v0 = src[0], v1 = src[1], v2 = src[2], v3 = src[3];
        uint2 u;
        int b = r * 512 + t8 * 32;
        u.x = pkbf(v0[0], v0[1]); u.y = pkbf(v0[2], v0[3]);
        *reinterpret_cast<uint2*>(&Abuf[swz(b, r)]) = u;
        u.x = pkbf(v1[0], v1[1]); u.y = pkbf(v1[2], v1[3]);
        *reinterpret_cast<uint2*>(&Abuf[swz(b + 8, r)]) = u;
        u.x = pkbf(v2[0], v2[1]); u.y = pkbf(v2[2], v2[3]);
        *reinterpret_cast<uint2*>(&Abuf[swz(b + 16, r)]) = u;
        u.x = pkbf(v3[0], v3[1]); u.y = pkbf(v3[2], v3[3]);
        *reinterpret_cast<uint2*>(&Abuf[swz(b + 24, r)]) = u;
    }
    // e2n: f32 gather-sum (4-way unrolled) -> A cols [128+t8*16, +16)
    {
        f32x4 a0 = {}, a1 = {}, a2 = {}, a3 = {};
        if (n < NN) {
            int p = offs[n];
            const int pe = offs[n + 1];
            for (; p + 3 < pe; p += 4) {
                int ea = adj[p], eb = adj[p + 1], ec = adj[p + 2], ed = adj[p + 3];
                const f32x4* ra = reinterpret_cast<const f32x4*>(edge_out + (size_t)ea * RR + t8 * 16);
                const f32x4* rb = reinterpret_cast<const f32x4*>(edge_out + (size_t)eb * RR + t8 * 16);
                const f32x4* rc = reinterpret_cast<const f32x4*>(edge_out + (size_t)ec * RR + t8 * 16);
                const f32x4* rd = reinterpret_cast<const f32x4*>(edge_out + (size_t)ed * RR + t8 * 16);
                a0 += ra[0]; a1 += ra[1]; a2 += ra[2]; a3 += ra[3];
                a0 += rb[0]; a1 += rb[1]; a2 += rb[2]; a3 += rb[3];
                a0 += rc[0]; a1 += rc[1]; a2 += rc[2]; a3 += rc[3];
                a0 += rd[0]; a1 += rd[1]; a2 += rd[2]; a3 += rd[3];
            }
            for (; p < pe; ++p) {
                int e = adj[p];
                const f32x4* rr = reinterpret_cast<const f32x4*>(edge_out + (size_t)e * RR + t8 * 16);
                a0 += rr[0]; a1 += rr[1]; a2 += rr[2]; a3 += rr[3];
            }
        }
        uint2 u;
        int b = r * 512 + 256 + t8 * 32;
        u.x = pkbf(a0[0], a0[1]); u.y = pkbf(a0[2], a0[3]);
        *reinterpret_cast<uint2*>(&Abuf[swz(b, r)]) = u;
        u.x = pkbf(a1[0], a1[1]); u.y = pkbf(a1[2], a1[3]);
        *reinterpret_cast<uint2*>(&Abuf[swz(b + 8, r)]) = u;
        u.x = pkbf(a2[0], a2[1]); u.y = pkbf(a2[2], a2[3]);
        *reinterpret_cast<uint2*>(&Abuf[swz(b + 16, r)]) = u;
        u.x = pkbf(a3[0], a3[1]); u.y = pkbf(a3[2], a3[3]);
        *reinterpret_cast<uint2*>(&Abuf[swz(b + 24, r)]) = u;
    }
    __syncthreads();

    const int lane = tid & 63, wave = tid >> 6;
    const int l15 = lane & 15, l4 = lane >> 4;
    const int hbase = wave * 32;

    // GEMM1: k = 256
    f32x4 acc[2][4] = {};
    #pragma unroll
    for (int kk = 0; kk < 8; ++kk) {
        const int koel = kk * 32 + l4 * 8;
        short8 bfr[4];
        #pragma unroll
        for (int et = 0; et < 4; ++et) {
            int rw = et * 16 + l15;
            bfr[et] = *reinterpret_cast<const short8*>(&Abuf[swz(rw * 512 + koel * 2, rw)]);
        }
        #pragma unroll
        for (int ht = 0; ht < 2; ++ht) {
            short8 afr = *reinterpret_cast<const short8*>(
                w1t + (size_t)(hbase + ht * 16 + l15) * 256 + koel);
            #pragma unroll
            for (int et = 0; et < 4; ++et)
                acc[ht][et] = __builtin_amdgcn_mfma_f32_16x16x32_bf16(afr, bfr[et], acc[ht][et], 0, 0, 0);
        }
    }
    __syncthreads();   // A reads done; alias H

    #pragma unroll
    for (int ht = 0; ht < 2; ++ht) {
        const int h0 = hbase + ht * 16 + l4 * 4;
        float4 bb = *reinterpret_cast<const float4*>(b1 + h0);
        #pragma unroll
        for (int et = 0; et < 4; ++et) {
            int e = et * 16 + l15;
            float x0 = fmaxf(acc[ht][et][0] + bb.x, 0.f);
            float x1 = fmaxf(acc[ht][et][1] + bb.y, 0.f);
            float x2 = fmaxf(acc[ht][et][2] + bb.z, 0.f);
            float x3 = fmaxf(acc[ht][et][3] + bb.w, 0.f);
            uint2 u; u.x = pkbf(x0, x1); u.y = pkbf(x2, x3);
            *reinterpret_cast<uint2*>(&Abuf[swz(e * 512 + h0 * 2, e)]) = u;
        }
    }
    __syncthreads();

    // GEMM2
    f32x4 acc2[4] = {};
    const int cbase = wave * 16;
    #pragma unroll
    for (int kk = 0; kk < 256; kk += 32) {
        const int koel = kk + l4 * 8;
        short8 afr = *reinterpret_cast<const short8*>(
            w2t + (size_t)(cbase + l15) * 256 + koel);
        #pragma unroll
        for (int et = 0; et < 4; ++et) {
            int rw = et * 16 + l15;
            short8 bfr = *reinterpret_cast<const short8*>(&Abuf[swz(rw * 512 + koel * 2, rw)]);
            acc2[et] = __builtin_amdgcn_mfma_f32_16x16x32_bf16(afr, bfr, acc2[et], 0, 0, 0);
        }
    }

    {
        const int c0 = cbase + l4 * 4;
        float4 bb = *reinterpret_cast<const float4*>(b2 + c0);
        #pragma unroll
        for (int et = 0; et < 4; ++et) {
            int nn2 = n0 + et * 16 + l15;
            if (nn2 < NN) {
                float4 v;
                v.x = acc2[et][0] + bb.x;
                v.y = acc2[et][1] + bb.y;
                v.z = acc2[et][2] + bb.z;
                v.w = acc2[et][3] + bb.w;
                *reinterpret_cast<float4*>(out + (size_t)nn2 * RR + c0) = v;
            }
        }
    }
}

extern "C" void kernel_launch(void* const* d_in, const int* in_sizes, int n_in,
                              void* d_out, int out_size, void* d_ws, size_t ws_size,
                              hipStream_t stream) {
    const float* node_rep  = (const float*)d_in[0];
    const float* edge_attr = (const float*)d_in[1];
    const int*   esrc      = (const int*)d_in[2];
    const int*   edst      = (const int*)d_in[3];
    const float* W1e = (const float*)d_in[4];
    const float* b1e = (const float*)d_in[5];
    const float* W2e = (const float*)d_in[6];
    const float* b2e = (const float*)d_in[7];
    const float* W1n = (const float*)d_in[8];
    const float* b1n = (const float*)d_in[9];
    const float* W2n = (const float*)d_in[10];
    const float* b2n = (const float*)d_in[11];

    float* out      = (float*)d_out;
    float* node_out = out;                          // N*R
    float* edge_out = out + (size_t)NN * RR;        // E*R

    // workspace layout (bytes)
    char* ws = (char*)d_ws;
    unsigned short* w1et = (unsigned short*)ws;                 // [256][384]
    unsigned short* w2et = w1et + 256 * 384;                    // [128][256]
    unsigned short* w1nt = w2et + 128 * 256;                    // [256][256]
    unsigned short* w2nt = w1nt + 256 * 256;                    // [128][256]
    size_t off = 458752;
    int* cnt  = (int*)(ws + off);               off += 400000;  // [NN] (fill cursor)
    int* offs = (int*)(ws + off);               off += 400008;  // [NN+1]
    int* adj  = (int*)(ws + off);               off += 4800000; // [2*NE]
    int* bsum = (int*)(ws + off);               off += 512;     // [NB_SCAN]

    hipMemsetAsync(cnt, 0, (size_t)NN * sizeof(int), stream);

    transpose_cast<<<(384 * 256 + 255) / 256, 256, 0, stream>>>(W1e, w1et, 384, 256);
    transpose_cast<<<(256 * 128 + 255) / 256, 256, 0, stream>>>(W2e, w2et, 256, 128);
    transpose_cast<<<(256 * 256 + 255) / 256, 256, 0, stream>>>(W1n, w1nt, 256, 256);
    transpose_cast<<<(256 * 128 + 255) / 256, 256, 0, stream>>>(W2n, w2nt, 256, 128);

    count_kernel<<<(NE + 255) / 256, 256, 0, stream>>>(esrc, edst, cnt);
    scan_part<<<NB_SCAN, 1024, 0, stream>>>(cnt, offs, bsum);
    scan_tops<<<1, 64, 0, stream>>>(bsum, offs + NN);
    scan_add<<<NB_SCAN, 1024, 0, stream>>>(offs, bsum, cnt);
    fill_kernel<<<(NE + 255) / 256, 256, 0, stream>>>(esrc, edst, cnt, adj);

    edge_kernel<<<NE / 64, 512, 0, stream>>>(node_rep, edge_attr, esrc, edst,
                                             w1et, b1e, w2et, b2e, edge_out);

    node_kernel<<<(NN + 63) / 64, 512, 0, stream>>>(node_rep, offs, adj, edge_out,
                                                    w1nt, b1n, w2nt, b2n, node_out);
}

// Round 8
// 853.015 us; speedup vs baseline: 1.6172x; 1.4099x over previous
//
#include <hip/hip_runtime.h>

typedef __attribute__((ext_vector_type(8))) short short8;
typedef __attribute__((ext_vector_type(4))) float f32x4;

#define NN 100000
#define NE 600000
#define RR 128
#define HH 256
#define NB_SCAN 98     // ceil(NN/1024)
#define SEGB 16384     // per-seg LDS bytes (64 rows x 256B)

__device__ __forceinline__ unsigned short f2bf(float f) {
    unsigned u = __builtin_bit_cast(unsigned, f);
    u = (u + 0x7fffu + ((u >> 16) & 1u)) >> 16;   // RNE
    return (unsigned short)u;
}

// pack two f32 -> one dword of 2 bf16 (round-half-up), 3 VALU ops
__device__ __forceinline__ unsigned pkbf(float lo, float hi) {
    unsigned a = __builtin_bit_cast(unsigned, lo) + 0x8000u;
    unsigned b = __builtin_bit_cast(unsigned, hi) + 0x8000u;
    return __builtin_amdgcn_perm(b, a, 0x07060302);  // {b.hi16, a.hi16}
}

// LDS XOR swizzle: spread 16B blocks of a row across bank groups
__device__ __forceinline__ int swz(int byteoff, int row) {
    return byteoff ^ ((row & 7) << 4);
}

__global__ __launch_bounds__(256) void transpose_cast(const float* __restrict__ src,
                                                      unsigned short* __restrict__ dst,
                                                      int K, int C) {
    int i = blockIdx.x * 256 + threadIdx.x;
    if (i >= K * C) return;
    int c = i / K, k = i - c * K;
    dst[i] = f2bf(src[k * C + c]);   // dst[c][k] = src[k][c]
}

// ---------------- CSR build ----------------
__global__ __launch_bounds__(256) void count_kernel(const int* __restrict__ esrc,
                                                    const int* __restrict__ edst,
                                                    int* __restrict__ cnt) {
    int i = blockIdx.x * 256 + threadIdx.x;
    if (i < NE) {
        atomicAdd(&cnt[esrc[i]], 1);
        atomicAdd(&cnt[edst[i]], 1);
    }
}

__global__ __launch_bounds__(1024) void scan_part(const int* __restrict__ cnt,
                                                  int* __restrict__ excl,
                                                  int* __restrict__ bsum) {
    __shared__ int wsum[16];
    const int tid = threadIdx.x;
    const int lane = tid & 63, w = tid >> 6;
    int i = blockIdx.x * 1024 + tid;
    int v = (i < NN) ? cnt[i] : 0;
    int s = v;
    #pragma unroll
    for (int d = 1; d < 64; d <<= 1) {
        int t = __shfl_up(s, d, 64);
        if (lane >= d) s += t;
    }
    if (lane == 63) wsum[w] = s;
    __syncthreads();
    if (w == 0) {
        int x = (lane < 16) ? wsum[lane] : 0;
        int sx = x;
        #pragma unroll
        for (int d = 1; d < 16; d <<= 1) {
            int t = __shfl_up(sx, d, 64);
            if (lane >= d) sx += t;
        }
        if (lane < 16) wsum[lane] = sx - x;          // exclusive wave offset
        if (lane == 15) bsum[blockIdx.x] = sx;       // block total
    }
    __syncthreads();
    if (i < NN) excl[i] = wsum[w] + (s - v);
}

__global__ void scan_tops(int* __restrict__ bsum, int* __restrict__ offs_nn) {
    if (threadIdx.x == 0) {
        int run = 0;
        for (int b = 0; b < NB_SCAN; ++b) { int t = bsum[b]; bsum[b] = run; run += t; }
        *offs_nn = run;   // offs[NN] = 2*NE
    }
}

__global__ __launch_bounds__(1024) void scan_add(int* __restrict__ offs,
                                                 const int* __restrict__ bsum,
                                                 int* __restrict__ cur) {
    int i = blockIdx.x * 1024 + threadIdx.x;
    if (i < NN) { int v = offs[i] + bsum[blockIdx.x]; offs[i] = v; cur[i] = v; }
}

__global__ __launch_bounds__(256) void fill_kernel(const int* __restrict__ esrc,
                                                   const int* __restrict__ edst,
                                                   int* __restrict__ cur,
                                                   int* __restrict__ adj) {
    int i = blockIdx.x * 256 + threadIdx.x;
    if (i < NE) {
        int p = atomicAdd(&cur[esrc[i]], 1);
        adj[p] = i;
        int q = atomicAdd(&cur[edst[i]], 1);
        adj[q] = i;
    }
}

// ---------------- edge kernel: seg-dbuf staging + MLP (32KB LDS, 8 waves, no spill) ----------------
__global__ __launch_bounds__(512, 6) void edge_kernel(
    const float* __restrict__ node_rep, const float* __restrict__ edge_attr,
    const int* __restrict__ esrc, const int* __restrict__ edst,
    const unsigned short* __restrict__ w1t, const float* __restrict__ b1,
    const unsigned short* __restrict__ w2t, const float* __restrict__ b2,
    float* __restrict__ edge_out)
{
    __shared__ char Sbuf[2 * SEGB];   // two 16KB seg buffers; H aliases all 32KB
    const int tid = threadIdx.x;
    const int e0 = blockIdx.x * 64;
    const int lane = tid & 63, wave = tid >> 6;
    const int l15 = lane & 15, l4 = lane >> 4;
    const int hbase = wave * 32;

    // lane r holds endpoint indices of edge e0+r (same across all waves)
    const int sv = esrc[e0 + lane];
    const int dv = edst[e0 + lane];

    // staging geometry: 512 threads cover 64 rows x 32 float4 per seg
    const int c4 = tid & 31;
    const int row_b = tid >> 5;           // add j*16, j=0..3

    float4 ga[4];

    // ---- stage segA (edge_attr) -> S0 ----
    #pragma unroll
    for (int j = 0; j < 4; ++j) {
        int row = row_b + j * 16;
        ga[j] = *reinterpret_cast<const float4*>(edge_attr + (size_t)(e0 + row) * RR + c4 * 4);
    }
    #pragma unroll
    for (int j = 0; j < 4; ++j) {
        int row = row_b + j * 16;
        uint2 u; u.x = pkbf(ga[j].x, ga[j].y); u.y = pkbf(ga[j].z, ga[j].w);
        *reinterpret_cast<uint2*>(&Sbuf[swz(row * 256 + c4 * 8, row)]) = u;
    }
    __syncthreads();   // S0 = segA ready

    f32x4 acc[2][4] = {};

#define GEMM1_SEG(SEGIDX, SBASE)                                                     \
    _Pragma("unroll")                                                                \
    for (int kk2 = 0; kk2 < 4; ++kk2) {                                              \
        const int koel = kk2 * 32 + l4 * 8;                                          \
        short8 bfr[4];                                                               \
        _Pragma("unroll")                                                            \
        for (int et = 0; et < 4; ++et) {                                             \
            int rw = et * 16 + l15;                                                  \
            bfr[et] = *reinterpret_cast<const short8*>(                              \
                &Sbuf[(SBASE) + swz(rw * 256 + koel * 2, rw)]);                      \
        }                                                                            \
        _Pragma("unroll")                                                            \
        for (int ht = 0; ht < 2; ++ht) {                                             \
            short8 afr = *reinterpret_cast<const short8*>(                           \
                w1t + (size_t)(hbase + ht * 16 + l15) * 384 + (SEGIDX) * 128 + koel);\
            _Pragma("unroll")                                                        \
            for (int et = 0; et < 4; ++et)                                           \
                acc[ht][et] = __builtin_amdgcn_mfma_f32_16x16x32_bf16(               \
                    afr, bfr[et], acc[ht][et], 0, 0, 0);                             \
        }                                                                            \
    }

    // ---- issue segB loads (src nodes); compute segA; write segB -> S1 ----
    #pragma unroll
    for (int j = 0; j < 4; ++j) {
        int row = row_b + j * 16;
        int ns = __shfl(sv, row);
        ga[j] = *reinterpret_cast<const float4*>(node_rep + (size_t)ns * RR + c4 * 4);
    }
    GEMM1_SEG(0, 0)
    #pragma unroll
    for (int j = 0; j < 4; ++j) {
        int row = row_b + j * 16;
        uint2 u; u.x = pkbf(ga[j].x, ga[j].y); u.y = pkbf(ga[j].z, ga[j].w);
        *reinterpret_cast<uint2*>(&Sbuf[SEGB + swz(row * 256 + c4 * 8, row)]) = u;
    }
    __syncthreads();   // S1 = segB ready (S0 fully consumed)

    // ---- issue segC loads (dst nodes); compute segB; write segC -> S0 ----
    #pragma unroll
    for (int j = 0; j < 4; ++j) {
        int row = row_b + j * 16;
        int nd = __shfl(dv, row);
        ga[j] = *reinterpret_cast<const float4*>(node_rep + (size_t)nd * RR + c4 * 4);
    }
    GEMM1_SEG(1, SEGB)
    #pragma unroll
    for (int j = 0; j < 4; ++j) {
        int row = row_b + j * 16;
        uint2 u; u.x = pkbf(ga[j].x, ga[j].y); u.y = pkbf(ga[j].z, ga[j].w);
        *reinterpret_cast<uint2*>(&Sbuf[swz(row * 256 + c4 * 8, row)]) = u;
    }
    __syncthreads();   // S0 = segC ready (S1 consumed)

    GEMM1_SEG(2, 0)
    __syncthreads();   // all A reads done; alias H over full 32KB
#undef GEMM1_SEG

    // ---- H = relu(acc + b1) -> bf16 LDS (row stride 512B, swizzled) ----
    #pragma unroll
    for (int ht = 0; ht < 2; ++ht) {
        const int h0 = hbase + ht * 16 + l4 * 4;
        float4 bb = *reinterpret_cast<const float4*>(b1 + h0);
        #pragma unroll
        for (int et = 0; et < 4; ++et) {
            int e = et * 16 + l15;
            float x0 = fmaxf(acc[ht][et][0] + bb.x, 0.f);
            float x1 = fmaxf(acc[ht][et][1] + bb.y, 0.f);
            float x2 = fmaxf(acc[ht][et][2] + bb.z, 0.f);
            float x3 = fmaxf(acc[ht][et][3] + bb.w, 0.f);
            uint2 u; u.x = pkbf(x0, x1); u.y = pkbf(x2, x3);
            *reinterpret_cast<uint2*>(&Sbuf[swz(e * 512 + h0 * 2, e)]) = u;
        }
    }
    __syncthreads();   // H ready

    // ---- GEMM2': D2'[c][e] = sum_h W2T[c][h] * H[e][h] ----
    f32x4 acc2[4] = {};
    const int cbase = wave * 16;
    #pragma unroll
    for (int kk = 0; kk < 256; kk += 32) {
        const int koel = kk + l4 * 8;
        short8 afr = *reinterpret_cast<const short8*>(
            w2t + (size_t)(cbase + l15) * 256 + koel);
        #pragma unroll
        for (int et = 0; et < 4; ++et) {
            int rw = et * 16 + l15;
            short8 bfr = *reinterpret_cast<const short8*>(&Sbuf[swz(rw * 512 + koel * 2, rw)]);
            acc2[et] = __builtin_amdgcn_mfma_f32_16x16x32_bf16(afr, bfr, acc2[et], 0, 0, 0);
        }
    }

    // ---- epilogue: bias + store edge_out ----
    {
        const int c0 = cbase + l4 * 4;
        float4 bb = *reinterpret_cast<const float4*>(b2 + c0);
        #pragma unroll
        for (int et = 0; et < 4; ++et) {
            int e = et * 16 + l15;
            float4 v;
            v.x = acc2[et][0] + bb.x;
            v.y = acc2[et][1] + bb.y;
            v.z = acc2[et][2] + bb.z;
            v.w = acc2[et][3] + bb.w;
            *reinterpret_cast<float4*>(edge_out + (size_t)(e0 + e) * RR + c0) = v;
        }
    }
}

// ---------------- node kernel: unrolled CSR pull + MLP -> node_out ----------------
__global__ __launch_bounds__(512, 5) void node_kernel(
    const float* __restrict__ node_rep,
    const int* __restrict__ offs, const int* __restrict__ adj,
    const float* __restrict__ edge_out,
    const unsigned short* __restrict__ w1t, const float* __restrict__ b1,
    const unsigned short* __restrict__ w2t, const float* __restrict__ b2,
    float* __restrict__ out)
{
    __shared__ char Abuf[64 * 512];   // A-tile (256 bf16/row); H aliases after GEMM1
    const int tid = threadIdx.x;
    const int n0 = blockIdx.x * 64;
    const int r = tid >> 3, t8 = tid & 7;     // 8 threads/row, 16 elements each
    const int n = n0 + r;
    const int nc = (n < NN) ? n : NN - 1;

    // node_rep -> A cols [t8*16, +16)
    {
        const f32x4* src = reinterpret_cast<const f32x4*>(node_rep + (size_t)nc * RR + t8 * 16);
        f32x4 v0 = src[0], v1 = src[1], v2 = src[2], v3 = src[3];
        uint2 u;
        int b = r * 512 + t8 * 32;
        u.x = pkbf(v0[0], v0[1]); u.y = pkbf(v0[2], v0[3]);
        *reinterpret_cast<uint2*>(&Abuf[swz(b, r)]) = u;
        u.x = pkbf(v1[0], v1[1]); u.y = pkbf(v1[2], v1[3]);
        *reinterpret_cast<uint2*>(&Abuf[swz(b + 8, r)]) = u;
        u.x = pkbf(v2[0], v2[1]); u.y = pkbf(v2[2], v2[3]);
        *reinterpret_cast<uint2*>(&Abuf[swz(b + 16, r)]) = u;
        u.x = pkbf(v3[0], v3[1]); u.y = pkbf(v3[2], v3[3]);
        *reinterpret_cast<uint2*>(&Abuf[swz(b + 24, r)]) = u;
    }
    // e2n: f32 gather-sum (4-way unrolled) -> A cols [128+t8*16, +16)
    {
        f32x4 a0 = {}, a1 = {}, a2 = {}, a3 = {};
        if (n < NN) {
            int p = offs[n];
            const int pe = offs[n + 1];
            for (; p + 3 < pe; p += 4) {
                int ea = adj[p], eb = adj[p + 1], ec = adj[p + 2], ed = adj[p + 3];
                const f32x4* ra = reinterpret_cast<const f32x4*>(edge_out + (size_t)ea * RR + t8 * 16);
                const f32x4* rb = reinterpret_cast<const f32x4*>(edge_out + (size_t)eb * RR + t8 * 16);
                const f32x4* rc = reinterpret_cast<const f32x4*>(edge_out + (size_t)ec * RR + t8 * 16);
                const f32x4* rd = reinterpret_cast<const f32x4*>(edge_out + (size_t)ed * RR + t8 * 16);
                a0 += ra[0]; a1 += ra[1]; a2 += ra[2]; a3 += ra[3];
                a0 += rb[0]; a1 += rb[1]; a2 += rb[2]; a3 += rb[3];
                a0 += rc[0]; a1 += rc[1]; a2 += rc[2]; a3 += rc[3];
                a0 += rd[0]; a1 += rd[1]; a2 += rd[2]; a3 += rd[3];
            }
            for (; p < pe; ++p) {
                int e = adj[p];
                const f32x4* rr = reinterpret_cast<const f32x4*>(edge_out + (size_t)e * RR + t8 * 16);
                a0 += rr[0]; a1 += rr[1]; a2 += rr[2]; a3 += rr[3];
            }
        }
        uint2 u;
        int b = r * 512 + 256 + t8 * 32;
        u.x = pkbf(a0[0], a0[1]); u.y = pkbf(a0[2], a0[3]);
        *reinterpret_cast<uint2*>(&Abuf[swz(b, r)]) = u;
        u.x = pkbf(a1[0], a1[1]); u.y = pkbf(a1[2], a1[3]);
        *reinterpret_cast<uint2*>(&Abuf[swz(b + 8, r)]) = u;
        u.x = pkbf(a2[0], a2[1]); u.y = pkbf(a2[2], a2[3]);
        *reinterpret_cast<uint2*>(&Abuf[swz(b + 16, r)]) = u;
        u.x = pkbf(a3[0], a3[1]); u.y = pkbf(a3[2], a3[3]);
        *reinterpret_cast<uint2*>(&Abuf[swz(b + 24, r)]) = u;
    }
    __syncthreads();

    const int lane = tid & 63, wave = tid >> 6;
    const int l15 = lane & 15, l4 = lane >> 4;
    const int hbase = wave * 32;

    // GEMM1: k = 256
    f32x4 acc[2][4] = {};
    #pragma unroll
    for (int kk = 0; kk < 8; ++kk) {
        const int koel = kk * 32 + l4 * 8;
        short8 bfr[4];
        #pragma unroll
        for (int et = 0; et < 4; ++et) {
            int rw = et * 16 + l15;
            bfr[et] = *reinterpret_cast<const short8*>(&Abuf[swz(rw * 512 + koel * 2, rw)]);
        }
        #pragma unroll
        for (int ht = 0; ht < 2; ++ht) {
            short8 afr = *reinterpret_cast<const short8*>(
                w1t + (size_t)(hbase + ht * 16 + l15) * 256 + koel);
            #pragma unroll
            for (int et = 0; et < 4; ++et)
                acc[ht][et] = __builtin_amdgcn_mfma_f32_16x16x32_bf16(afr, bfr[et], acc[ht][et], 0, 0, 0);
        }
    }
    __syncthreads();   // A reads done; alias H

    #pragma unroll
    for (int ht = 0; ht < 2; ++ht) {
        const int h0 = hbase + ht * 16 + l4 * 4;
        float4 bb = *reinterpret_cast<const float4*>(b1 + h0);
        #pragma unroll
        for (int et = 0; et < 4; ++et) {
            int e = et * 16 + l15;
            float x0 = fmaxf(acc[ht][et][0] + bb.x, 0.f);
            float x1 = fmaxf(acc[ht][et][1] + bb.y, 0.f);
            float x2 = fmaxf(acc[ht][et][2] + bb.z, 0.f);
            float x3 = fmaxf(acc[ht][et][3] + bb.w, 0.f);
            uint2 u; u.x = pkbf(x0, x1); u.y = pkbf(x2, x3);
            *reinterpret_cast<uint2*>(&Abuf[swz(e * 512 + h0 * 2, e)]) = u;
        }
    }
    __syncthreads();

    // GEMM2
    f32x4 acc2[4] = {};
    const int cbase = wave * 16;
    #pragma unroll
    for (int kk = 0; kk < 256; kk += 32) {
        const int koel = kk + l4 * 8;
        short8 afr = *reinterpret_cast<const short8*>(
            w2t + (size_t)(cbase + l15) * 256 + koel);
        #pragma unroll
        for (int et = 0; et < 4; ++et) {
            int rw = et * 16 + l15;
            short8 bfr = *reinterpret_cast<const short8*>(&Abuf[swz(rw * 512 + koel * 2, rw)]);
            acc2[et] = __builtin_amdgcn_mfma_f32_16x16x32_bf16(afr, bfr, acc2[et], 0, 0, 0);
        }
    }

    {
        const int c0 = cbase + l4 * 4;
        float4 bb = *reinterpret_cast<const float4*>(b2 + c0);
        #pragma unroll
        for (int et = 0; et < 4; ++et) {
            int nn2 = n0 + et * 16 + l15;
            if (nn2 < NN) {
                float4 v;
                v.x = acc2[et][0] + bb.x;
                v.y = acc2[et][1] + bb.y;
                v.z = acc2[et][2] + bb.z;
                v.w = acc2[et][3] + bb.w;
                *reinterpret_cast<float4*>(out + (size_t)nn2 * RR + c0) = v;
            }
        }
    }
}

extern "C" void kernel_launch(void* const* d_in, const int* in_sizes, int n_in,
                              void* d_out, int out_size, void* d_ws, size_t ws_size,
                              hipStream_t stream) {
    const float* node_rep  = (const float*)d_in[0];
    const float* edge_attr = (const float*)d_in[1];
    const int*   esrc      = (const int*)d_in[2];
    const int*   edst      = (const int*)d_in[3];
    const float* W1e = (const float*)d_in[4];
    const float* b1e = (const float*)d_in[5];
    const float* W2e = (const float*)d_in[6];
    const float* b2e = (const float*)d_in[7];
    const float* W1n = (const float*)d_in[8];
    const float* b1n = (const float*)d_in[9];
    const float* W2n = (const float*)d_in[10];
    const float* b2n = (const float*)d_in[11];

    float* out      = (float*)d_out;
    float* node_out = out;                          // N*R
    float* edge_out = out + (size_t)NN * RR;        // E*R

    // workspace layout (bytes)
    char* ws = (char*)d_ws;
    unsigned short* w1et = (unsigned short*)ws;                 // [256][384]
    unsigned short* w2et = w1et + 256 * 384;                    // [128][256]
    unsigned short* w1nt = w2et + 128 * 256;                    // [256][256]
    unsigned short* w2nt = w1nt + 256 * 256;                    // [128][256]
    size_t off = 458752;
    int* cnt  = (int*)(ws + off);               off += 400000;  // [NN] (fill cursor)
    int* offs = (int*)(ws + off);               off += 400008;  // [NN+1]
    int* adj  = (int*)(ws + off);               off += 4800000; // [2*NE]
    int* bsum = (int*)(ws + off);               off += 512;     // [NB_SCAN]

    hipMemsetAsync(cnt, 0, (size_t)NN * sizeof(int), stream);

    transpose_cast<<<(384 * 256 + 255) / 256, 256, 0, stream>>>(W1e, w1et, 384, 256);
    transpose_cast<<<(256 * 128 + 255) / 256, 256, 0, stream>>>(W2e, w2et, 256, 128);
    transpose_cast<<<(256 * 256 + 255) / 256, 256, 0, stream>>>(W1n, w1nt, 256, 256);
    transpose_cast<<<(256 * 128 + 255) / 256, 256, 0, stream>>>(W2n, w2nt, 256, 128);

    count_kernel<<<(NE + 255) / 256, 256, 0, stream>>>(esrc, edst, cnt);
    scan_part<<<NB_SCAN, 1024, 0, stream>>>(cnt, offs, bsum);
    scan_tops<<<1, 64, 0, stream>>>(bsum, offs + NN);
    scan_add<<<NB_SCAN, 1024, 0, stream>>>(offs, bsum, cnt);
    fill_kernel<<<(NE + 255) / 256, 256, 0, stream>>>(esrc, edst, cnt, adj);

    edge_kernel<<<NE / 64, 512, 0, stream>>>(node_rep, edge_attr, esrc, edst,
                                             w1et, b1e, w2et, b2e, edge_out);

    node_kernel<<<(NN + 63) / 64, 512, 0, stream>>>(node_rep, offs, adj, edge_out,
                                                    w1nt, b1n, w2nt, b2n, node_out);
}

// Round 9
// 733.550 us; speedup vs baseline: 1.8806x; 1.1629x over previous
//
#include <hip/hip_runtime.h>

typedef __attribute__((ext_vector_type(8))) short short8;
typedef __attribute__((ext_vector_type(4))) float f32x4;

#define NN 100000
#define NE 600000
#define RR 128
#define HH 256
#define NB_SCAN 98     // ceil(NN/1024)
#define SEGB 16384     // per-seg LDS bytes (64 rows x 256B)

typedef const __attribute__((address_space(1))) void* gvp;
typedef __attribute__((address_space(3))) void* lvp;
typedef __attribute__((address_space(3))) char* lcp;

__device__ __forceinline__ unsigned short f2bf(float f) {
    unsigned u = __builtin_bit_cast(unsigned, f);
    u = (u + 0x7fffu + ((u >> 16) & 1u)) >> 16;   // RNE
    return (unsigned short)u;
}

// pack two f32 -> one dword of 2 bf16 (round-half-up), 3 VALU ops
__device__ __forceinline__ unsigned pkbf(float lo, float hi) {
    unsigned a = __builtin_bit_cast(unsigned, lo) + 0x8000u;
    unsigned b = __builtin_bit_cast(unsigned, hi) + 0x8000u;
    return __builtin_amdgcn_perm(b, a, 0x07060302);  // {b.hi16, a.hi16}
}

// LDS XOR swizzle: spread 16B blocks of a row across bank groups
__device__ __forceinline__ int swz(int byteoff, int row) {
    return byteoff ^ ((row & 7) << 4);
}

__global__ __launch_bounds__(256) void transpose_cast(const float* __restrict__ src,
                                                      unsigned short* __restrict__ dst,
                                                      int K, int C) {
    int i = blockIdx.x * 256 + threadIdx.x;
    if (i >= K * C) return;
    int c = i / K, k = i - c * K;
    dst[i] = f2bf(src[k * C + c]);   // dst[c][k] = src[k][c]
}

// cast f32 array -> bf16 (4 elems/thread)
__global__ __launch_bounds__(256) void cast_bf16(const float* __restrict__ src,
                                                 unsigned short* __restrict__ dst,
                                                 int n4) {
    int i = blockIdx.x * 256 + threadIdx.x;
    if (i >= n4) return;
    float4 v = *reinterpret_cast<const float4*>(src + i * 4);
    uint2 u;
    u.x = f2bf(v.x) | ((unsigned)f2bf(v.y) << 16);
    u.y = f2bf(v.z) | ((unsigned)f2bf(v.w) << 16);
    *reinterpret_cast<uint2*>(dst + i * 4) = u;
}

// ---------------- CSR build ----------------
__global__ __launch_bounds__(256) void count_kernel(const int* __restrict__ esrc,
                                                    const int* __restrict__ edst,
                                                    int* __restrict__ cnt) {
    int i = blockIdx.x * 256 + threadIdx.x;
    if (i < NE) {
        atomicAdd(&cnt[esrc[i]], 1);
        atomicAdd(&cnt[edst[i]], 1);
    }
}

__global__ __launch_bounds__(1024) void scan_part(const int* __restrict__ cnt,
                                                  int* __restrict__ excl,
                                                  int* __restrict__ bsum) {
    __shared__ int wsum[16];
    const int tid = threadIdx.x;
    const int lane = tid & 63, w = tid >> 6;
    int i = blockIdx.x * 1024 + tid;
    int v = (i < NN) ? cnt[i] : 0;
    int s = v;
    #pragma unroll
    for (int d = 1; d < 64; d <<= 1) {
        int t = __shfl_up(s, d, 64);
        if (lane >= d) s += t;
    }
    if (lane == 63) wsum[w] = s;
    __syncthreads();
    if (w == 0) {
        int x = (lane < 16) ? wsum[lane] : 0;
        int sx = x;
        #pragma unroll
        for (int d = 1; d < 16; d <<= 1) {
            int t = __shfl_up(sx, d, 64);
            if (lane >= d) sx += t;
        }
        if (lane < 16) wsum[lane] = sx - x;          // exclusive wave offset
        if (lane == 15) bsum[blockIdx.x] = sx;       // block total
    }
    __syncthreads();
    if (i < NN) excl[i] = wsum[w] + (s - v);
}

__global__ void scan_tops(int* __restrict__ bsum, int* __restrict__ offs_nn) {
    if (threadIdx.x == 0) {
        int run = 0;
        for (int b = 0; b < NB_SCAN; ++b) { int t = bsum[b]; bsum[b] = run; run += t; }
        *offs_nn = run;   // offs[NN] = 2*NE
    }
}

__global__ __launch_bounds__(1024) void scan_add(int* __restrict__ offs,
                                                 const int* __restrict__ bsum,
                                                 int* __restrict__ cur) {
    int i = blockIdx.x * 1024 + threadIdx.x;
    if (i < NN) { int v = offs[i] + bsum[blockIdx.x]; offs[i] = v; cur[i] = v; }
}

__global__ __launch_bounds__(256) void fill_kernel(const int* __restrict__ esrc,
                                                   const int* __restrict__ edst,
                                                   int* __restrict__ cur,
                                                   int* __restrict__ adj) {
    int i = blockIdx.x * 256 + threadIdx.x;
    if (i < NE) {
        int p = atomicAdd(&cur[esrc[i]], 1);
        adj[p] = i;
        int q = atomicAdd(&cur[edst[i]], 1);
        adj[q] = i;
    }
}

// ---- edge kernel: DMA gather staging (global_load_lds) + MLP, 32KB dbuf ----
__global__ __launch_bounds__(512, 5) void edge_kernel(
    const unsigned short* __restrict__ nr16, const float* __restrict__ edge_attr,
    const int* __restrict__ esrc, const int* __restrict__ edst,
    const unsigned short* __restrict__ w1t, const float* __restrict__ b1,
    const unsigned short* __restrict__ w2t, const float* __restrict__ b2,
    float* __restrict__ edge_out)
{
    __shared__ char Sbuf[2 * SEGB];   // two 16KB seg buffers; H aliases all 32KB
    lcp SbufL = (lcp)Sbuf;
    const int tid = threadIdx.x;
    const int e0 = blockIdx.x * 64;
    const int lane = tid & 63, wave = tid >> 6;
    const int l15 = lane & 15, l4 = lane >> 4;
    const int hbase = wave * 32;

    // staging geometry for segA (f32 path): 512 threads cover 64 rows x 32 float4
    const int c4 = tid & 31;
    const int row_b = tid >> 5;           // add j*16, j=0..3

    // ---- prologue: issue segA f32 loads ----
    float4 ga[4];
    #pragma unroll
    for (int j = 0; j < 4; ++j) {
        int row = row_b + j * 16;
        ga[j] = *reinterpret_cast<const float4*>(edge_attr + (size_t)(e0 + row) * RR + c4 * 4);
    }

    // ---- issue segB DMA (src node rows, bf16, swizzled source) -> S1 ----
    {
        int r0 = wave * 8 + (lane >> 4);
        int r1 = r0 + 4;
        int i0 = esrc[e0 + r0];
        int i1 = esrc[e0 + r1];
        const char* g0 = (const char*)nr16 + (size_t)i0 * 256 + (((lane & 15) ^ (r0 & 7)) << 4);
        const char* g1 = (const char*)nr16 + (size_t)i1 * 256 + (((lane & 15) ^ (r1 & 7)) << 4);
        __builtin_amdgcn_global_load_lds((gvp)g0, (lvp)(SbufL + SEGB + wave * 2048), 16, 0, 0);
        __builtin_amdgcn_global_load_lds((gvp)g1, (lvp)(SbufL + SEGB + wave * 2048 + 1024), 16, 0, 0);
    }

    // ---- pack segA -> S0 ----
    #pragma unroll
    for (int j = 0; j < 4; ++j) {
        int row = row_b + j * 16;
        uint2 u; u.x = pkbf(ga[j].x, ga[j].y); u.y = pkbf(ga[j].z, ga[j].w);
        *reinterpret_cast<uint2*>(&Sbuf[swz(row * 256 + c4 * 8, row)]) = u;
    }
    __syncthreads();   // S0 = segA ready, S1 = segB ready (vmcnt drained)

    f32x4 acc[2][4] = {};

#define GEMM1_SEG(SEGIDX, SBASE)                                                     \
    _Pragma("unroll")                                                                \
    for (int kk2 = 0; kk2 < 4; ++kk2) {                                              \
        const int koel = kk2 * 32 + l4 * 8;                                          \
        short8 bfr[4];                                                               \
        _Pragma("unroll")                                                            \
        for (int et = 0; et < 4; ++et) {                                             \
            int rw = et * 16 + l15;                                                  \
            bfr[et] = *reinterpret_cast<const short8*>(                              \
                &Sbuf[(SBASE) + swz(rw * 256 + koel * 2, rw)]);                      \
        }                                                                            \
        _Pragma("unroll")                                                            \
        for (int ht = 0; ht < 2; ++ht) {                                             \
            short8 afr = *reinterpret_cast<const short8*>(                           \
                w1t + (size_t)(hbase + ht * 16 + l15) * 384 + (SEGIDX) * 128 + koel);\
            _Pragma("unroll")                                                        \
            for (int et = 0; et < 4; ++et)                                           \
                acc[ht][et] = __builtin_amdgcn_mfma_f32_16x16x32_bf16(               \
                    afr, bfr[et], acc[ht][et], 0, 0, 0);                             \
        }                                                                            \
    }

    // ---- GEMM segA (S0) ----
    GEMM1_SEG(0, 0)
    __syncthreads();   // S0 free

    // ---- issue segC DMA (dst node rows) -> S0; GEMM segB (S1) ----
    {
        int r0 = wave * 8 + (lane >> 4);
        int r1 = r0 + 4;
        int i0 = edst[e0 + r0];
        int i1 = edst[e0 + r1];
        const char* g0 = (const char*)nr16 + (size_t)i0 * 256 + (((lane & 15) ^ (r0 & 7)) << 4);
        const char* g1 = (const char*)nr16 + (size_t)i1 * 256 + (((lane & 15) ^ (r1 & 7)) << 4);
        __builtin_amdgcn_global_load_lds((gvp)g0, (lvp)(SbufL + wave * 2048), 16, 0, 0);
        __builtin_amdgcn_global_load_lds((gvp)g1, (lvp)(SbufL + wave * 2048 + 1024), 16, 0, 0);
    }
    GEMM1_SEG(1, SEGB)
    __syncthreads();   // S0 = segC ready (DMA drained), S1 free

    GEMM1_SEG(2, 0)
    __syncthreads();   // all A reads done; alias H over full 32KB
#undef GEMM1_SEG

    // ---- H = relu(acc + b1) -> bf16 LDS (row stride 512B, swizzled) ----
    #pragma unroll
    for (int ht = 0; ht < 2; ++ht) {
        const int h0 = hbase + ht * 16 + l4 * 4;
        float4 bb = *reinterpret_cast<const float4*>(b1 + h0);
        #pragma unroll
        for (int et = 0; et < 4; ++et) {
            int e = et * 16 + l15;
            float x0 = fmaxf(acc[ht][et][0] + bb.x, 0.f);
            float x1 = fmaxf(acc[ht][et][1] + bb.y, 0.f);
            float x2 = fmaxf(acc[ht][et][2] + bb.z, 0.f);
            float x3 = fmaxf(acc[ht][et][3] + bb.w, 0.f);
            uint2 u; u.x = pkbf(x0, x1); u.y = pkbf(x2, x3);
            *reinterpret_cast<uint2*>(&Sbuf[swz(e * 512 + h0 * 2, e)]) = u;
        }
    }
    __syncthreads();   // H ready

    // ---- GEMM2': D2'[c][e] = sum_h W2T[c][h] * H[e][h] ----
    f32x4 acc2[4] = {};
    const int cbase = wave * 16;
    #pragma unroll
    for (int kk = 0; kk < 256; kk += 32) {
        const int koel = kk + l4 * 8;
        short8 afr = *reinterpret_cast<const short8*>(
            w2t + (size_t)(cbase + l15) * 256 + koel);
        #pragma unroll
        for (int et = 0; et < 4; ++et) {
            int rw = et * 16 + l15;
            short8 bfr = *reinterpret_cast<const short8*>(&Sbuf[swz(rw * 512 + koel * 2, rw)]);
            acc2[et] = __builtin_amdgcn_mfma_f32_16x16x32_bf16(afr, bfr, acc2[et], 0, 0, 0);
        }
    }

    // ---- epilogue: bias + store edge_out ----
    {
        const int c0 = cbase + l4 * 4;
        float4 bb = *reinterpret_cast<const float4*>(b2 + c0);
        #pragma unroll
        for (int et = 0; et < 4; ++et) {
            int e = et * 16 + l15;
            float4 v;
            v.x = acc2[et][0] + bb.x;
            v.y = acc2[et][1] + bb.y;
            v.z = acc2[et][2] + bb.z;
            v.w = acc2[et][3] + bb.w;
            *reinterpret_cast<float4*>(edge_out + (size_t)(e0 + e) * RR + c0) = v;
        }
    }
}

// ---------------- node kernel: unrolled CSR pull + MLP -> node_out ----------------
__global__ __launch_bounds__(512, 5) void node_kernel(
    const float* __restrict__ node_rep,
    const int* __restrict__ offs, const int* __restrict__ adj,
    const float* __restrict__ edge_out,
    const unsigned short* __restrict__ w1t, const float* __restrict__ b1,
    const unsigned short* __restrict__ w2t, const float* __restrict__ b2,
    float* __restrict__ out)
{
    __shared__ char Abuf[64 * 512];   // A-tile (256 bf16/row); H aliases after GEMM1
    const int tid = threadIdx.x;
    const int n0 = blockIdx.x * 64;
    const int r = tid >> 3, t8 = tid & 7;     // 8 threads/row, 16 elements each
    const int n = n0 + r;
    const int nc = (n < NN) ? n : NN - 1;

    // node_rep -> A cols [t8*16, +16)
    {
        const f32x4* src = reinterpret_cast<const f32x4*>(node_rep + (size_t)nc * RR + t8 * 16);
        f32x4 v0 = src[0], v1 = src[1], v2 = src[2], v3 = src[3];
        uint2 u;
        int b = r * 512 + t8 * 32;
        u.x = pkbf(v0[0], v0[1]); u.y = pkbf(v0[2], v0[3]);
        *reinterpret_cast<uint2*>(&Abuf[swz(b, r)]) = u;
        u.x = pkbf(v1[0], v1[1]); u.y = pkbf(v1[2], v1[3]);
        *reinterpret_cast<uint2*>(&Abuf[swz(b + 8, r)]) = u;
        u.x = pkbf(v2[0], v2[1]); u.y = pkbf(v2[2], v2[3]);
        *reinterpret_cast<uint2*>(&Abuf[swz(b + 16, r)]) = u;
        u.x = pkbf(v3[0], v3[1]); u.y = pkbf(v3[2], v3[3]);
        *reinterpret_cast<uint2*>(&Abuf[swz(b + 24, r)]) = u;
    }
    // e2n: f32 gather-sum (4-way unrolled) -> A cols [128+t8*16, +16)
    {
        f32x4 a0 = {}, a1 = {}, a2 = {}, a3 = {};
        if (n < NN) {
            int p = offs[n];
            const int pe = offs[n + 1];
            for (; p + 3 < pe; p += 4) {
                int ea = adj[p], eb = adj[p + 1], ec = adj[p + 2], ed = adj[p + 3];
                const f32x4* ra = reinterpret_cast<const f32x4*>(edge_out + (size_t)ea * RR + t8 * 16);
                const f32x4* rb = reinterpret_cast<const f32x4*>(edge_out + (size_t)eb * RR + t8 * 16);
                const f32x4* rc = reinterpret_cast<const f32x4*>(edge_out + (size_t)ec * RR + t8 * 16);
                const f32x4* rd = reinterpret_cast<const f32x4*>(edge_out + (size_t)ed * RR + t8 * 16);
                a0 += ra[0]; a1 += ra[1]; a2 += ra[2]; a3 += ra[3];
                a0 += rb[0]; a1 += rb[1]; a2 += rb[2]; a3 += rb[3];
                a0 += rc[0]; a1 += rc[1]; a2 += rc[2]; a3 += rc[3];
                a0 += rd[0]; a1 += rd[1]; a2 += rd[2]; a3 += rd[3];
            }
            for (; p < pe; ++p) {
                int e = adj[p];
                const f32x4* rr = reinterpret_cast<const f32x4*>(edge_out + (size_t)e * RR + t8 * 16);
                a0 += rr[0]; a1 += rr[1]; a2 += rr[2]; a3 += rr[3];
            }
        }
        uint2 u;
        int b = r * 512 + 256 + t8 * 32;
        u.x = pkbf(a0[0], a0[1]); u.y = pkbf(a0[2], a0[3]);
        *reinterpret_cast<uint2*>(&Abuf[swz(b, r)]) = u;
        u.x = pkbf(a1[0], a1[1]); u.y = pkbf(a1[2], a1[3]);
        *reinterpret_cast<uint2*>(&Abuf[swz(b + 8, r)]) = u;
        u.x = pkbf(a2[0], a2[1]); u.y = pkbf(a2[2], a2[3]);
        *reinterpret_cast<uint2*>(&Abuf[swz(b + 16, r)]) = u;
        u.x = pkbf(a3[0], a3[1]); u.y = pkbf(a3[2], a3[3]);
        *reinterpret_cast<uint2*>(&Abuf[swz(b + 24, r)]) = u;
    }
    __syncthreads();

    const int lane = tid & 63, wave = tid >> 6;
    const int l15 = lane & 15, l4 = lane >> 4;
    const int hbase = wave * 32;

    // GEMM1: k = 256
    f32x4 acc[2][4] = {};
    #pragma unroll
    for (int kk = 0; kk < 8; ++kk) {
        const int koel = kk * 32 + l4 * 8;
        short8 bfr[4];
        #pragma unroll
        for (int et = 0; et < 4; ++et) {
            int rw = et * 16 + l15;
            bfr[et] = *reinterpret_cast<const short8*>(&Abuf[swz(rw * 512 + koel * 2, rw)]);
        }
        #pragma unroll
        for (int ht = 0; ht < 2; ++ht) {
            short8 afr = *reinterpret_cast<const short8*>(
                w1t + (size_t)(hbase + ht * 16 + l15) * 256 + koel);
            #pragma unroll
            for (int et = 0; et < 4; ++et)
                acc[ht][et] = __builtin_amdgcn_mfma_f32_16x16x32_bf16(afr, bfr[et], acc[ht][et], 0, 0, 0);
        }
    }
    __syncthreads();   // A reads done; alias H

    #pragma unroll
    for (int ht = 0; ht < 2; ++ht) {
        const int h0 = hbase + ht * 16 + l4 * 4;
        float4 bb = *reinterpret_cast<const float4*>(b1 + h0);
        #pragma unroll
        for (int et = 0; et < 4; ++et) {
            int e = et * 16 + l15;
            float x0 = fmaxf(acc[ht][et][0] + bb.x, 0.f);
            float x1 = fmaxf(acc[ht][et][1] + bb.y, 0.f);
            float x2 = fmaxf(acc[ht][et][2] + bb.z, 0.f);
            float x3 = fmaxf(acc[ht][et][3] + bb.w, 0.f);
            uint2 u; u.x = pkbf(x0, x1); u.y = pkbf(x2, x3);
            *reinterpret_cast<uint2*>(&Abuf[swz(e * 512 + h0 * 2, e)]) = u;
        }
    }
    __syncthreads();

    // GEMM2
    f32x4 acc2[4] = {};
    const int cbase = wave * 16;
    #pragma unroll
    for (int kk = 0; kk < 256; kk += 32) {
        const int koel = kk + l4 * 8;
        short8 afr = *reinterpret_cast<const short8*>(
            w2t + (size_t)(cbase + l15) * 256 + koel);
        #pragma unroll
        for (int et = 0; et < 4; ++et) {
            int rw = et * 16 + l15;
            short8 bfr = *reinterpret_cast<const short8*>(&Abuf[swz(rw * 512 + koel * 2, rw)]);
            acc2[et] = __builtin_amdgcn_mfma_f32_16x16x32_bf16(afr, bfr, acc2[et], 0, 0, 0);
        }
    }

    {
        const int c0 = cbase + l4 * 4;
        float4 bb = *reinterpret_cast<const float4*>(b2 + c0);
        #pragma unroll
        for (int et = 0; et < 4; ++et) {
            int nn2 = n0 + et * 16 + l15;
            if (nn2 < NN) {
                float4 v;
                v.x = acc2[et][0] + bb.x;
                v.y = acc2[et][1] + bb.y;
                v.z = acc2[et][2] + bb.z;
                v.w = acc2[et][3] + bb.w;
                *reinterpret_cast<float4*>(out + (size_t)nn2 * RR + c0) = v;
            }
        }
    }
}

extern "C" void kernel_launch(void* const* d_in, const int* in_sizes, int n_in,
                              void* d_out, int out_size, void* d_ws, size_t ws_size,
                              hipStream_t stream) {
    const float* node_rep  = (const float*)d_in[0];
    const float* edge_attr = (const float*)d_in[1];
    const int*   esrc      = (const int*)d_in[2];
    const int*   edst      = (const int*)d_in[3];
    const float* W1e = (const float*)d_in[4];
    const float* b1e = (const float*)d_in[5];
    const float* W2e = (const float*)d_in[6];
    const float* b2e = (const float*)d_in[7];
    const float* W1n = (const float*)d_in[8];
    const float* b1n = (const float*)d_in[9];
    const float* W2n = (const float*)d_in[10];
    const float* b2n = (const float*)d_in[11];

    float* out      = (float*)d_out;
    float* node_out = out;                          // N*R
    float* edge_out = out + (size_t)NN * RR;        // E*R

    // workspace layout (bytes)
    char* ws = (char*)d_ws;
    unsigned short* w1et = (unsigned short*)ws;                 // [256][384]
    unsigned short* w2et = w1et + 256 * 384;                    // [128][256]
    unsigned short* w1nt = w2et + 128 * 256;                    // [256][256]
    unsigned short* w2nt = w1nt + 256 * 256;                    // [128][256]
    size_t off = 458752;
    unsigned short* nr16 = (unsigned short*)(ws + off); off += (size_t)NN * RR * 2;  // 25.6 MB
    int* cnt  = (int*)(ws + off);               off += 400000;  // [NN] (fill cursor)
    int* offs = (int*)(ws + off);               off += 400008;  // [NN+1]
    int* adj  = (int*)(ws + off);               off += 4800000; // [2*NE]
    int* bsum = (int*)(ws + off);               off += 512;     // [NB_SCAN]

    hipMemsetAsync(cnt, 0, (size_t)NN * sizeof(int), stream);

    transpose_cast<<<(384 * 256 + 255) / 256, 256, 0, stream>>>(W1e, w1et, 384, 256);
    transpose_cast<<<(256 * 128 + 255) / 256, 256, 0, stream>>>(W2e, w2et, 256, 128);
    transpose_cast<<<(256 * 256 + 255) / 256, 256, 0, stream>>>(W1n, w1nt, 256, 256);
    transpose_cast<<<(256 * 128 + 255) / 256, 256, 0, stream>>>(W2n, w2nt, 256, 128);
    cast_bf16<<<(NN * RR / 4 + 255) / 256, 256, 0, stream>>>(node_rep, nr16, NN * RR / 4);

    count_kernel<<<(NE + 255) / 256, 256, 0, stream>>>(esrc, edst, cnt);
    scan_part<<<NB_SCAN, 1024, 0, stream>>>(cnt, offs, bsum);
    scan_tops<<<1, 64, 0, stream>>>(bsum, offs + NN);
    scan_add<<<NB_SCAN, 1024, 0, stream>>>(offs, bsum, cnt);
    fill_kernel<<<(NE + 255) / 256, 256, 0, stream>>>(esrc, edst, cnt, adj);

    edge_kernel<<<NE / 64, 512, 0, stream>>>(nr16, edge_attr, esrc, edst,
                                             w1et, b1e, w2et, b2e, edge_out);

    node_kernel<<<(NN + 63) / 64, 512, 0, stream>>>(node_rep, offs, adj, edge_out,
                                                    w1nt, b1n, w2nt, b2n, node_out);
}